// Round 11
// baseline (4231.960 us; speedup 1.0000x reference)
//
#include <hip/hip_runtime.h>
#include <math.h>

// ---------------------------------------------------------------------------
// sLSTM block, round 11: r10's chain-batched MFMA scan (4 blocks x 16 chains,
// mfma_f32_16x16x32_f16, no gate replication) + r8's I/O discipline:
// proj staged per-step via global_load_lds (contiguous 32 KB slab, dbuf),
// h dumped via hstage LDS -> one coalesced dwordx4 per thread per step.
// Zero per-thread global address arithmetic on the step path.
// FFN = bf16 MFMA, post_kernel fuses headLN+residual+LN2-stats (unchanged).
// Workspace (floats): r0 32MB | state 128KB | mu/rs 256KB | w1b 8MB | w2b 4MB
// ---------------------------------------------------------------------------

#define D_MODEL 1024
#define NHEAD   8
#define DPH     128
#define DFF     2048
#define BATCH   8
#define SEQ     2048
#define NROWS   (BATCH * SEQ)   // 16384
#define CHUNK_L 256             // scan steps per launch (8 launches)
#define ROWCH   8192            // FFN rows per chunk (2 chunks)
#define LN_EPS  1e-5f
#define NCH     136             // hbuf row stride in f16 (272B, 16B-aligned)

typedef __attribute__((ext_vector_type(8))) short short8;
typedef __attribute__((ext_vector_type(4))) float f32x4;
typedef __attribute__((ext_vector_type(8))) _Float16 half8;

__device__ __forceinline__ float gelu_exact(float x) {
  return 0.5f * x * (1.0f + erff(x * 0.70710678118654752440f));
}

__device__ __forceinline__ unsigned short f2bf(float f) {
  union { float f; unsigned int u; } v; v.f = f;
  unsigned int r = v.u + 0x7fffu + ((v.u >> 16) & 1u);
  return (unsigned short)(r >> 16);
}

// async global->LDS, 16B per lane; lds_base must be WAVE-UNIFORM (HW adds lane*16)
__device__ __forceinline__ void gll16(const float* src, float* lds_base, int lane) {
#if __has_builtin(__builtin_amdgcn_global_load_lds)
  __builtin_amdgcn_global_load_lds(
      (const __attribute__((address_space(1))) unsigned int*)src,
      (__attribute__((address_space(3))) unsigned int*)lds_base, 16, 0, 0);
#else
  *(float4*)((char*)lds_base + lane * 16) = *(const float4*)src;
#endif
}

// one sLSTM gate update for one channel; returns raw h
__device__ __forceinline__ float gate_step(float iv, float fv, float zraw, float oraw,
                                           float& c, float& nrm, float& m) {
  const float zv = 1.0f - 2.0f / (__expf(2.0f * zraw) + 1.0f);
  const float ov = 1.0f / (1.0f + __expf(-oraw));
  const float lf = fminf(fv, 0.0f) - __logf(1.0f + __expf(-fabsf(fv)));
  const float ft = lf + m;
  const float mn = fmaxf(ft, iv);
  const float is = __expf(iv - mn);
  const float fs = __expf(ft - mn);
  c = fs * c + is * zv;
  nrm = fs * nrm + is;
  m = mn;
  return ov * (c / nrm);
}

// --------------------- per-row LN stats (mu, rstd) --------------------------
__global__ __launch_bounds__(256) void ln_stats_kernel(
    const float* __restrict__ in, float* __restrict__ mu_out,
    float* __restrict__ rs_out) {
  const int row = blockIdx.x, tid = threadIdx.x;
  const float4 v = ((const float4*)(in + (size_t)row * D_MODEL))[tid];
  float s  = v.x + v.y + v.z + v.w;
  float s2 = v.x*v.x + v.y*v.y + v.z*v.z + v.w*v.w;
  #pragma unroll
  for (int m = 1; m < 64; m <<= 1) { s += __shfl_xor(s, m, 64); s2 += __shfl_xor(s2, m, 64); }
  __shared__ float sa[4], sb[4];
  if ((tid & 63) == 0) { sa[tid >> 6] = s; sb[tid >> 6] = s2; }
  __syncthreads();
  if (tid == 0) {
    const float S  = sa[0] + sa[1] + sa[2] + sa[3];
    const float S2 = sb[0] + sb[1] + sb[2] + sb[3];
    const float mu = S * (1.0f / D_MODEL);
    const float var = S2 * (1.0f / D_MODEL) - mu * mu;
    mu_out[row] = mu;
    rs_out[row] = rsqrtf(var + LN_EPS);
  }
}

// -------------- weight convert+transpose: [K][N] f32 -> [N][K] bf16 ---------
__global__ __launch_bounds__(256) void cvt_w(
    const float* __restrict__ src, short* __restrict__ dst, int K, int N) {
  __shared__ float tile[64][68];
  const int n0 = blockIdx.x * 64;
  const int k0 = blockIdx.y * 64;
  const int tid = threadIdx.x;
  #pragma unroll
  for (int i = 0; i < 16; ++i) {
    const int e = i * 256 + tid;
    const int kk = e >> 6, nn = e & 63;
    tile[kk][nn] = src[(size_t)(k0 + kk) * N + n0 + nn];
  }
  __syncthreads();
  #pragma unroll
  for (int i = 0; i < 2; ++i) {
    const int e = i * 256 + tid;
    const int nn = e >> 3, kc = (e & 7) * 8;
    short8 s;
    #pragma unroll
    for (int j = 0; j < 8; ++j) s[j] = (short)f2bf(tile[kc + j][nn]);
    *(short8*)(dst + (size_t)(n0 + nn) * K + k0 + kc) = s;
  }
}

// --------------------------- head projection GEMM --------------------------
__global__ __launch_bounds__(256) void proj_gemm(
    const float* __restrict__ x, const float* __restrict__ mu1,
    const float* __restrict__ rs1, const float* __restrict__ ln1w,
    const float* __restrict__ ln1b, const float* __restrict__ ihw,
    const float* __restrict__ ihb, float* __restrict__ proj, int l0) {
  __shared__ __align__(16) float As[64][68];
  __shared__ __align__(16) float Bs[64][128];
  const int h  = blockIdx.z;
  const int n0 = blockIdx.y * 128;
  const int m0 = blockIdx.x * 64;
  const int tid = threadIdx.x;
  const int tm = (tid >> 5) << 3;
  const int tn = (tid & 31) << 2;
  float acc[8][4] = {};
  const float* Bb = ihw + (size_t)h * DPH * 512;
  for (int k0 = 0; k0 < DPH; k0 += 64) {
    #pragma unroll
    for (int i = 0; i < 4; ++i) {
      int idx = tid + i * 256;
      int r = idx >> 4, kk = (idx & 15) << 2;
      const int rowm = m0 + r;
      const int l = l0 + (rowm >> 3), b = rowm & 7;
      const int grow = b * SEQ + l;
      const float4 v = *(const float4*)(x + (size_t)grow * D_MODEL + h * DPH + k0 + kk);
      const float mu = mu1[grow], rs = rs1[grow];
      const float4 wv = *(const float4*)(ln1w + h * DPH + k0 + kk);
      const float4 bv = *(const float4*)(ln1b + h * DPH + k0 + kk);
      float4 o;
      o.x = (v.x - mu) * rs * wv.x + bv.x;
      o.y = (v.y - mu) * rs * wv.y + bv.y;
      o.z = (v.z - mu) * rs * wv.z + bv.z;
      o.w = (v.w - mu) * rs * wv.w + bv.w;
      *(float4*)&As[r][kk] = o;
    }
    #pragma unroll
    for (int i = 0; i < 8; ++i) {
      int idx = tid + i * 256;
      int kk = idx >> 5, nn = (idx & 31) << 2;
      *(float4*)&Bs[kk][nn] = *(const float4*)(Bb + (size_t)(k0 + kk) * 512 + n0 + nn);
    }
    __syncthreads();
    #pragma unroll 4
    for (int kk = 0; kk < 64; ++kk) {
      float a[8];
      #pragma unroll
      for (int i = 0; i < 8; ++i) a[i] = As[tm + i][kk];
      const float4 bv = *(const float4*)&Bs[kk][tn];
      #pragma unroll
      for (int i = 0; i < 8; ++i) {
        acc[i][0] += a[i] * bv.x; acc[i][1] += a[i] * bv.y;
        acc[i][2] += a[i] * bv.z; acc[i][3] += a[i] * bv.w;
      }
    }
    __syncthreads();
  }
  const float4 bias = *(const float4*)(ihb + h * 512 + n0 + tn);
  #pragma unroll
  for (int i = 0; i < 8; ++i) {
    const int rowm = m0 + tm + i;
    float4 o;
    o.x = acc[i][0] + bias.x; o.y = acc[i][1] + bias.y;
    o.z = acc[i][2] + bias.z; o.w = acc[i][3] + bias.w;
    // layout: (lrel*64 + b*8 + h)*512 + n  == [step][chain][n]
    *(float4*)(proj + ((size_t)rowm * NHEAD + h) * 512 + n0 + tn) = o;
  }
}

// ------------------------------- sLSTM scan --------------------------------
// 4 blocks x 16 chains, 512 threads / 8 waves. Fragment layouts (verified by
// the passing FFN kernels and r10's pass):
//   A[m][k]: m = lane&15 (=hbuf row), k = (lane>>4)*8 + j
//   B[k][n]: n = lane&15, k = (lane>>4)*8 + j          (W, register-resident)
//   D[m][n]: n-in-tile = lane&15, m = (lane>>4)*4 + r
// Wave w owns n-tiles {w,w+8,w+16,w+24} -> lane holds i,f,z,o (D[0..3][r]) for
// chain q*4+r, channel 16w+lo. proj staged via global_load_lds; h dumped via
// hstage LDS as one coalesced dwordx4/thread/step. One barrier per step.
__global__ __launch_bounds__(512, 1) void scan_chunk(
    const float* __restrict__ proj, const float* __restrict__ hhw,
    float* __restrict__ state, float* __restrict__ hout, int l0) {
  const int B = blockIdx.x;              // chains 16B .. 16B+15
  const int tid = threadIdx.x;
  const int l = tid & 63, w = tid >> 6;  // lane, wave
  const int q = l >> 4, lo = l & 15;
  const int ch = 16 * w + lo;            // this lane's gate channel
  __shared__ __align__(16) _Float16 hbuf[2][16][NCH];   // ~8.5 KB
  __shared__ __align__(16) float pbuf[2][8192];          // 64 KB staged proj
  __shared__ __align__(16) float hstage[2][16][128];     // 16 KB staged h

  // W fragments: wfrag[ti][s][j] = W[k=32s+8q+j][n=16(w+8ti)+lo]
  half8 wfrag[4][4];
  #pragma unroll
  for (int ti = 0; ti < 4; ++ti)
    #pragma unroll
    for (int s = 0; s < 4; ++s)
      #pragma unroll
      for (int j = 0; j < 8; ++j)
        wfrag[ti][s][j] =
            (_Float16)hhw[(size_t)(32 * s + 8 * q + j) * 512 + 16 * (w + 8 * ti) + lo];

  // per-lane state for chains q*4+r (r=0..3), channel ch
  float cst[4], nst[4], mst[4];
  if (l0 == 0) {
    #pragma unroll
    for (int r = 0; r < 4; ++r) {
      cst[r] = 0.0f; nst[r] = 0.0f; mst[r] = -1e30f;
      hbuf[1][q * 4 + r][ch] = (_Float16)0.0f;       // h(-1) = 0
    }
  } else {
    #pragma unroll
    for (int r = 0; r < 4; ++r) {
      const int bh = 16 * B + q * 4 + r;
      cst[r] = state[bh * 128 + ch];
      nst[r] = state[8192 + bh * 128 + ch];
      mst[r] = state[16384 + bh * 128 + ch];
      hbuf[1][q * 4 + r][ch] = (_Float16)state[24576 + bh * 128 + ch];
    }
  }

  // proj slab for this block at step t: contiguous 8192 floats at
  // pbase + t*32768  (layout [step][chain][n], chains 16B..16B+15)
  const float* pbase = proj + (size_t)16 * B * 512;

  // stage step T into pbuf half NB: 4 issues x (512 threads x 16B) = 32 KB
  #define STAGE(NB, T)                                                     \
    {                                                                      \
      _Pragma("unroll")                                                    \
      for (int i = 0; i < 4; ++i) {                                        \
        const float* src = pbase + (size_t)(T) * 32768 + i * 2048 + tid * 4; \
        float* dst = &pbuf[NB][0] + i * 2048 + w * 256;                    \
        gll16(src, dst, l);                                                \
      }                                                                    \
    }

  STAGE(0, 0)
  asm volatile("s_waitcnt vmcnt(0)" ::: "memory");
  __syncthreads();                                   // pbuf[0] + hbuf[1] ready

  f32x4 D[4];
  // D(0) = proj(0) + W . h(-1)
  {
    half8 af[4];
    #pragma unroll
    for (int s = 0; s < 4; ++s)
      af[s] = *(const half8*)&hbuf[1][lo][32 * s + 8 * q];
    #pragma unroll
    for (int ti = 0; ti < 4; ++ti) {
      f32x4 acc;
      #pragma unroll
      for (int r = 0; r < 4; ++r)
        acc[r] = pbuf[0][(q * 4 + r) * 512 + 16 * w + lo + 128 * ti];
      #pragma unroll
      for (int s = 0; s < 4; ++s)
        acc = __builtin_amdgcn_mfma_f32_16x16x32_f16(af[s], wfrag[ti][s], acc, 0, 0, 0);
      D[ti] = acc;
    }
  }

  float hv[4] = {0.0f, 0.0f, 0.0f, 0.0f};
  for (int t = 0; t < CHUNK_L; ++t) {
    const int buf = t & 1;
    // issue next step's staging (async; drained at this step's barrier)
    if (t + 1 < CHUNK_L) STAGE(buf ^ 1, t + 1)
    // gates: i,f,z,o for chain q*4+r live in D[0..3][r] of THIS lane
    _Float16* hb = &hbuf[0][0][0] + buf * 16 * NCH;
    float*    hs = &hstage[0][0][0] + buf * 2048;
    #pragma unroll
    for (int r = 0; r < 4; ++r) {
      hv[r] = gate_step(D[0][r], D[1][r], D[2][r], D[3][r], cst[r], nst[r], mst[r]);
      hb[(q * 4 + r) * NCH + ch] = (_Float16)hv[r];
      hs[(q * 4 + r) * 128 + ch] = hv[r];
    }
    __syncthreads();        // h(t)/hstage(t) visible; pbuf[(t+1)&1] drained
    // coalesced h dump: one dwordx4/thread; chains 0-7 -> batch 2B, 8-15 -> 2B+1
    {
      const int half = tid >> 8, idx = tid & 255;
      const float4 v = ((const float4*)(hs + half * 1024))[idx];
      *(float4*)(hout + (size_t)((2 * B + half) * SEQ + l0 + t) * D_MODEL + idx * 4) = v;
    }
    if (t + 1 == CHUNK_L) break;
    // D(t+1) = proj(t+1) + W . h(t)
    const float* pc = &pbuf[0][0] + (buf ^ 1) * 8192;
    half8 af[4];
    #pragma unroll
    for (int s = 0; s < 4; ++s)
      af[s] = *(const half8*)&hb[lo * NCH + 32 * s + 8 * q];
    #pragma unroll
    for (int ti = 0; ti < 4; ++ti) {
      f32x4 acc;
      #pragma unroll
      for (int r = 0; r < 4; ++r)
        acc[r] = pc[(q * 4 + r) * 512 + 16 * w + lo + 128 * ti];
      #pragma unroll
      for (int s = 0; s < 4; ++s)
        acc = __builtin_amdgcn_mfma_f32_16x16x32_f16(af[s], wfrag[ti][s], acc, 0, 0, 0);
      D[ti] = acc;
    }
  }

  #pragma unroll
  for (int r = 0; r < 4; ++r) {
    const int bh = 16 * B + q * 4 + r;
    state[bh * 128 + ch]          = cst[r];
    state[8192 + bh * 128 + ch]   = nst[r];
    state[16384 + bh * 128 + ch]  = mst[r];
    state[24576 + bh * 128 + ch]  = hv[r];
  }
  #undef STAGE
}

// ---------- post: y = headLN(h) + x in place on d_out ; LN2 row stats -------
__global__ __launch_bounds__(256) void post_kernel(
    float* __restrict__ yio, const float* __restrict__ x,
    const float* __restrict__ hnw, const float* __restrict__ hnb,
    float* __restrict__ mu2, float* __restrict__ rs2) {
  const int row = blockIdx.x, tid = threadIdx.x;
  const float4 hv = ((const float4*)(yio + (size_t)row * D_MODEL))[tid];
  float s  = hv.x + hv.y + hv.z + hv.w;
  float s2 = hv.x*hv.x + hv.y*hv.y + hv.z*hv.z + hv.w*hv.w;
  #pragma unroll
  for (int mm = 1; mm < 32; mm <<= 1) {
    s  += __shfl_xor(s,  mm, 32);
    s2 += __shfl_xor(s2, mm, 32);
  }
  const float mu = s * (1.0f / DPH);
  const float var = s2 * (1.0f / DPH) - mu * mu;
  const float rstd = rsqrtf(var + LN_EPS);
  const int dq = tid & 31;
  const float4 w4 = ((const float4*)hnw)[dq];
  const float4 b4 = ((const float4*)hnb)[dq];
  const float4 xv = ((const float4*)(x + (size_t)row * D_MODEL))[tid];
  float4 yv;
  yv.x = (hv.x - mu) * rstd * w4.x + b4.x + xv.x;
  yv.y = (hv.y - mu) * rstd * w4.y + b4.y + xv.y;
  yv.z = (hv.z - mu) * rstd * w4.z + b4.z + xv.z;
  yv.w = (hv.w - mu) * rstd * w4.w + b4.w + xv.w;
  ((float4*)(yio + (size_t)row * D_MODEL))[tid] = yv;
  float t1 = yv.x + yv.y + yv.z + yv.w;
  float t2 = yv.x*yv.x + yv.y*yv.y + yv.z*yv.z + yv.w*yv.w;
  #pragma unroll
  for (int mm = 1; mm < 64; mm <<= 1) {
    t1 += __shfl_xor(t1, mm, 64);
    t2 += __shfl_xor(t2, mm, 64);
  }
  __shared__ float sa[4], sb[4];
  if ((tid & 63) == 0) { sa[tid >> 6] = t1; sb[tid >> 6] = t2; }
  __syncthreads();
  if (tid == 0) {
    const float S  = sa[0] + sa[1] + sa[2] + sa[3];
    const float S2 = sb[0] + sb[1] + sb[2] + sb[3];
    const float m2 = S * (1.0f / D_MODEL);
    const float v2 = S2 * (1.0f / D_MODEL) - m2 * m2;
    mu2[row] = m2;
    rs2[row] = rsqrtf(v2 + LN_EPS);
  }
}

// ------------------------------ FF1 (bf16 MFMA) ------------------------------
__global__ __launch_bounds__(256) void ff1_gemm(
    const float* __restrict__ y, const float* __restrict__ mu2,
    const float* __restrict__ rs2, const float* __restrict__ ln2w,
    const float* __restrict__ ln2b, const short* __restrict__ w1b,
    const float* __restrict__ b1, short* __restrict__ g, int row0) {
  __shared__ short As[128 * 64];
  __shared__ short Bs1[128 * 64];
  __shared__ short Bs2[128 * 64];
  const int tid = threadIdx.x;
  const int m0 = blockIdx.x * 128;
  const int n0 = blockIdx.y * 128;
  const int lane = tid & 63;
  const int wid = tid >> 6, wr = wid >> 1, wc = wid & 1;
  f32x4 acc1[4][4], acc2[4][4];
  #pragma unroll
  for (int i = 0; i < 4; ++i)
    #pragma unroll
    for (int j = 0; j < 4; ++j) { acc1[i][j] = (f32x4)0.0f; acc2[i][j] = (f32x4)0.0f; }
  for (int k0 = 0; k0 < D_MODEL; k0 += 64) {
    #pragma unroll
    for (int i = 0; i < 4; ++i) {
      const int cidx = tid + i * 256;
      const int r = cidx >> 3, c8 = cidx & 7;
      const int grow = row0 + m0 + r;
      const float* src = y + (size_t)grow * D_MODEL + k0 + c8 * 8;
      const float4 v0 = *(const float4*)src;
      const float4 v1 = *(const float4*)(src + 4);
      const float mu = mu2[grow], rs = rs2[grow];
      const float4 w0 = *(const float4*)(ln2w + k0 + c8 * 8);
      const float4 w1 = *(const float4*)(ln2w + k0 + c8 * 8 + 4);
      const float4 bb0 = *(const float4*)(ln2b + k0 + c8 * 8);
      const float4 bb1 = *(const float4*)(ln2b + k0 + c8 * 8 + 4);
      short8 s;
      s[0] = (short)f2bf((v0.x - mu) * rs * w0.x + bb0.x);
      s[1] = (short)f2bf((v0.y - mu) * rs * w0.y + bb0.y);
      s[2] = (short)f2bf((v0.z - mu) * rs * w0.z + bb0.z);
      s[3] = (short)f2bf((v0.w - mu) * rs * w0.w + bb0.w);
      s[4] = (short)f2bf((v1.x - mu) * rs * w1.x + bb1.x);
      s[5] = (short)f2bf((v1.y - mu) * rs * w1.y + bb1.y);
      s[6] = (short)f2bf((v1.z - mu) * rs * w1.z + bb1.z);
      s[7] = (short)f2bf((v1.w - mu) * rs * w1.w + bb1.w);
      *(short8*)&As[r * 64 + ((c8 ^ (r & 7)) << 3)] = s;
    }
    #pragma unroll
    for (int i = 0; i < 4; ++i) {
      const int cidx = tid + i * 256;
      const int r = cidx >> 3, c8 = cidx & 7;
      const short8 sv1 = *(const short8*)(w1b + (size_t)(n0 + r) * D_MODEL + k0 + c8 * 8);
      const short8 sv2 = *(const short8*)(w1b + (size_t)(DFF + n0 + r) * D_MODEL + k0 + c8 * 8);
      const int off = r * 64 + ((c8 ^ (r & 7)) << 3);
      *(short8*)&Bs1[off] = sv1;
      *(short8*)&Bs2[off] = sv2;
    }
    __syncthreads();
    #pragma unroll
    for (int ks = 0; ks < 2; ++ks) {
      short8 af[4], b1f[4], b2f[4];
      #pragma unroll
      for (int mf = 0; mf < 4; ++mf) {
        const int row = wr * 64 + mf * 16 + (lane & 15);
        const int c8 = ks * 4 + (lane >> 4);
        af[mf] = *(const short8*)&As[row * 64 + ((c8 ^ (row & 7)) << 3)];
      }
      #pragma unroll
      for (int nf = 0; nf < 4; ++nf) {
        const int row = wc * 64 + nf * 16 + (lane & 15);
        const int c8 = ks * 4 + (lane >> 4);
        const int off = row * 64 + ((c8 ^ (row & 7)) << 3);
        b1f[nf] = *(const short8*)&Bs1[off];
        b2f[nf] = *(const short8*)&Bs2[off];
      }
      #pragma unroll
      for (int mf = 0; mf < 4; ++mf)
        #pragma unroll
        for (int nf = 0; nf < 4; ++nf) {
          acc1[mf][nf] = __builtin_amdgcn_mfma_f32_16x16x32_bf16(af[mf], b1f[nf], acc1[mf][nf], 0, 0, 0);
          acc2[mf][nf] = __builtin_amdgcn_mfma_f32_16x16x32_bf16(af[mf], b2f[nf], acc2[mf][nf], 0, 0, 0);
        }
    }
    __syncthreads();
  }
  #pragma unroll
  for (int nf = 0; nf < 4; ++nf) {
    const int col = n0 + wc * 64 + nf * 16 + (lane & 15);
    const float bx1 = b1[col], bx2 = b1[DFF + col];
    #pragma unroll
    for (int mf = 0; mf < 4; ++mf) {
      const int rbase = m0 + wr * 64 + mf * 16 + ((lane >> 4) << 2);
      #pragma unroll
      for (int rr = 0; rr < 4; ++rr) {
        const float x1 = acc1[mf][nf][rr] + bx1;
        const float x2 = acc2[mf][nf][rr] + bx2;
        g[(size_t)(rbase + rr) * DFF + col] = (short)f2bf(x1 * gelu_exact(x2));
      }
    }
  }
}

// ----------------- FF2 (bf16 MFMA) + bias + residual, in place --------------
__global__ __launch_bounds__(256) void ff2_gemm(
    const short* __restrict__ g, const short* __restrict__ w2b,
    const float* __restrict__ b2, float* __restrict__ out, int row0) {
  __shared__ short As[128 * 64];
  __shared__ short Bs[128 * 64];
  const int tid = threadIdx.x;
  const int m0 = blockIdx.x * 128;
  const int n0 = blockIdx.y * 128;
  const int lane = tid & 63;
  const int wid = tid >> 6, wr = wid >> 1, wc = wid & 1;
  f32x4 acc[4][4];
  #pragma unroll
  for (int i = 0; i < 4; ++i)
    #pragma unroll
    for (int j = 0; j < 4; ++j) acc[i][j] = (f32x4)0.0f;
  for (int k0 = 0; k0 < DFF; k0 += 64) {
    #pragma unroll
    for (int i = 0; i < 4; ++i) {
      const int cidx = tid + i * 256;
      const int r = cidx >> 3, c8 = cidx & 7;
      const int off = r * 64 + ((c8 ^ (r & 7)) << 3);
      *(short8*)&As[off] = *(const short8*)(g + (size_t)(m0 + r) * DFF + k0 + c8 * 8);
      *(short8*)&Bs[off] = *(const short8*)(w2b + (size_t)(n0 + r) * DFF + k0 + c8 * 8);
    }
    __syncthreads();
    #pragma unroll
    for (int ks = 0; ks < 2; ++ks) {
      short8 af[4], bf[4];
      #pragma unroll
      for (int mf = 0; mf < 4; ++mf) {
        const int row = wr * 64 + mf * 16 + (lane & 15);
        const int c8 = ks * 4 + (lane >> 4);
        af[mf] = *(const short8*)&As[row * 64 + ((c8 ^ (row & 7)) << 3)];
      }
      #pragma unroll
      for (int nf = 0; nf < 4; ++nf) {
        const int row = wc * 64 + nf * 16 + (lane & 15);
        const int c8 = ks * 4 + (lane >> 4);
        bf[nf] = *(const short8*)&Bs[row * 64 + ((c8 ^ (row & 7)) << 3)];
      }
      #pragma unroll
      for (int mf = 0; mf < 4; ++mf)
        #pragma unroll
        for (int nf = 0; nf < 4; ++nf)
          acc[mf][nf] = __builtin_amdgcn_mfma_f32_16x16x32_bf16(af[mf], bf[nf], acc[mf][nf], 0, 0, 0);
    }
    __syncthreads();
  }
  #pragma unroll
  for (int nf = 0; nf < 4; ++nf) {
    const int col = n0 + wc * 64 + nf * 16 + (lane & 15);
    const float bias = b2[col];
    #pragma unroll
    for (int mf = 0; mf < 4; ++mf) {
      const int rbase = row0 + m0 + wr * 64 + mf * 16 + ((lane >> 4) << 2);
      #pragma unroll
      for (int rr = 0; rr < 4; ++rr) {
        float* p = out + (size_t)(rbase + rr) * D_MODEL + col;
        *p = acc[mf][nf][rr] + bias + *p;
      }
    }
  }
}

// ------------------------------- launcher -----------------------------------
extern "C" void kernel_launch(void* const* d_in, const int* in_sizes, int n_in,
                              void* d_out, int out_size, void* d_ws, size_t ws_size,
                              hipStream_t stream) {
  const float* x    = (const float*)d_in[0];
  const float* ihw  = (const float*)d_in[1];
  const float* ihb  = (const float*)d_in[2];
  const float* hhw  = (const float*)d_in[3];
  const float* ln1w = (const float*)d_in[4];
  const float* ln1b = (const float*)d_in[5];
  const float* hnw  = (const float*)d_in[6];
  const float* hnb  = (const float*)d_in[7];
  const float* ln2w = (const float*)d_in[8];
  const float* ln2b = (const float*)d_in[9];
  const float* ffw1 = (const float*)d_in[10];
  const float* ffb1 = (const float*)d_in[11];
  const float* ffw2 = (const float*)d_in[12];
  const float* ffb2 = (const float*)d_in[13];

  float* ws    = (float*)d_ws;
  float* r0    = ws;                    // 8388608 floats: proj fp32 / g bf16
  float* state = ws + 8388608;          // 32768
  float* mu1   = ws + 8421376;
  float* rs1   = ws + 8437760;
  float* mu2   = ws + 8454144;
  float* rs2   = ws + 8470528;
  short* w1b   = (short*)(ws + 8486912);   // 4096x1024 bf16 (8 MB)
  short* w2b   = (short*)(ws + 10584064);  // 1024x2048 bf16 (4 MB)
  short* gb    = (short*)r0;               // 8192x2048 bf16 chunk (32 MB)
  float* out   = (float*)d_out;

  cvt_w<<<dim3(4096 / 64, 1024 / 64), 256, 0, stream>>>(ffw1, w1b, 1024, 4096);
  cvt_w<<<dim3(1024 / 64, 2048 / 64), 256, 0, stream>>>(ffw2, w2b, 2048, 1024);
  ln_stats_kernel<<<NROWS, 256, 0, stream>>>(x, mu1, rs1);
  for (int cidx = 0; cidx < SEQ / CHUNK_L; ++cidx) {
    const int l0 = cidx * CHUNK_L;
    proj_gemm<<<dim3(CHUNK_L * BATCH / 64, 512 / 128, NHEAD), 256, 0, stream>>>(
        x, mu1, rs1, ln1w, ln1b, ihw, ihb, r0, l0);
    scan_chunk<<<4, 512, 0, stream>>>(r0, hhw, state, out, l0);
  }
  post_kernel<<<NROWS, 256, 0, stream>>>(out, x, hnw, hnb, mu2, rs2);
  for (int rc = 0; rc < NROWS / ROWCH; ++rc) {
    const int row0 = rc * ROWCH;
    ff1_gemm<<<dim3(ROWCH / 128, DFF / 128), 256, 0, stream>>>(
        out, mu2, rs2, ln2w, ln2b, w1b, ffb1, gb, row0);
    ff2_gemm<<<dim3(ROWCH / 128, D_MODEL / 128), 256, 0, stream>>>(
        gb, w2b, ffb2, out, row0);
  }
}

// Round 12
// 2552.663 us; speedup vs baseline: 1.6579x; 1.6579x over previous
//
#include <hip/hip_runtime.h>
#include <math.h>

// ---------------------------------------------------------------------------
// sLSTM block, round 12: quad-gate scan. Matvec column for lane l of wave w is
// (l&3)*128 + 16w + (l>>2), so a channel's 4 gate pre-activations live in one
// quad -> exchanged with 4 v_mov_dpp quad_perm broadcasts (VALU, no LDS, no
// barrier). Gates computed once per channel (quad-replicated = free), each
// wave owns 16 channels -> NO inter-wave replication, NO p_lds round trip,
// ONE barrier/step. proj staged in 32-step groups via global_load_lds (r8
// pattern); h dumped coalesced per group. FFN = bf16 MFMA (unchanged).
// Workspace (floats): r0 32MB | state 128KB | mu/rs 256KB | w1b 8MB | w2b 4MB
//                     | hh2 128KB   (~44.6 MB)
// ---------------------------------------------------------------------------

#define D_MODEL 1024
#define NHEAD   8
#define DPH     128
#define DFF     2048
#define BATCH   8
#define SEQ     2048
#define NROWS   (BATCH * SEQ)   // 16384
#define CHUNK_L 256             // scan steps per launch (8 launches)
#define TGRP    32              // steps per staged group
#define ROWCH   8192            // FFN rows per chunk (2 chunks)
#define LN_EPS  1e-5f

typedef __attribute__((ext_vector_type(8))) short short8;
typedef __attribute__((ext_vector_type(4))) float f32x4;
typedef __attribute__((ext_vector_type(2))) _Float16 h2f;
typedef __attribute__((ext_vector_type(8))) _Float16 h8f;
union H8U { h8f v; h2f p[4]; };

#if __has_builtin(__builtin_amdgcn_fdot2)
#define DOT2(a, b, c) __builtin_amdgcn_fdot2((a), (b), (c), false)
#else
__device__ __forceinline__ float DOT2(h2f a, h2f b, float c) {
  return c + (float)a.x * (float)b.x + (float)a.y * (float)b.y;
}
#endif

// broadcast quad element J to all 4 lanes of each quad (DPP quad_perm)
template <int J>
__device__ __forceinline__ float qbcast(float v, int lane) {
#if __has_builtin(__builtin_amdgcn_update_dpp)
  union { float f; int i; } u; u.f = v;
  u.i = __builtin_amdgcn_update_dpp(u.i, u.i, J * 0x55, 0xf, 0xf, true);
  return u.f;
#else
  return __shfl(v, (lane & ~3) + J, 64);
#endif
}

// async global->LDS, 16B per lane; lds_base must be WAVE-UNIFORM (HW adds lane*16)
__device__ __forceinline__ void gll16(const float* src, float* lds_base, int lane) {
#if __has_builtin(__builtin_amdgcn_global_load_lds)
  __builtin_amdgcn_global_load_lds(
      (const __attribute__((address_space(1))) unsigned int*)src,
      (__attribute__((address_space(3))) unsigned int*)lds_base, 16, 0, 0);
#else
  *(float4*)((char*)lds_base + lane * 16) = *(const float4*)src;
#endif
}

__device__ __forceinline__ float gelu_exact(float x) {
  return 0.5f * x * (1.0f + erff(x * 0.70710678118654752440f));
}

__device__ __forceinline__ unsigned short f2bf(float f) {
  union { float f; unsigned int u; } v; v.f = f;
  unsigned int r = v.u + 0x7fffu + ((v.u >> 16) & 1u);
  return (unsigned short)(r >> 16);
}

// one sLSTM gate update for one channel; returns raw h
__device__ __forceinline__ float gate_step(float iv, float fv, float zraw, float oraw,
                                           float& c, float& nrm, float& m) {
  const float zv = 1.0f - 2.0f / (__expf(2.0f * zraw) + 1.0f);
  const float ov = 1.0f / (1.0f + __expf(-oraw));
  const float lf = fminf(fv, 0.0f) - __logf(1.0f + __expf(-fabsf(fv)));
  const float ft = lf + m;
  const float mn = fmaxf(ft, iv);
  const float is = __expf(iv - mn);
  const float fs = __expf(ft - mn);
  c = fs * c + is * zv;
  nrm = fs * nrm + is;
  m = mn;
  return ov * (c / nrm);
}

// --------------------- per-row LN stats (mu, rstd) --------------------------
__global__ __launch_bounds__(256) void ln_stats_kernel(
    const float* __restrict__ in, float* __restrict__ mu_out,
    float* __restrict__ rs_out) {
  const int row = blockIdx.x, tid = threadIdx.x;
  const float4 v = ((const float4*)(in + (size_t)row * D_MODEL))[tid];
  float s  = v.x + v.y + v.z + v.w;
  float s2 = v.x*v.x + v.y*v.y + v.z*v.z + v.w*v.w;
  #pragma unroll
  for (int m = 1; m < 64; m <<= 1) { s += __shfl_xor(s, m, 64); s2 += __shfl_xor(s2, m, 64); }
  __shared__ float sa[4], sb[4];
  if ((tid & 63) == 0) { sa[tid >> 6] = s; sb[tid >> 6] = s2; }
  __syncthreads();
  if (tid == 0) {
    const float S  = sa[0] + sa[1] + sa[2] + sa[3];
    const float S2 = sb[0] + sb[1] + sb[2] + sb[3];
    const float mu = S * (1.0f / D_MODEL);
    const float var = S2 * (1.0f / D_MODEL) - mu * mu;
    mu_out[row] = mu;
    rs_out[row] = rsqrtf(var + LN_EPS);
  }
}

// -------------- weight convert+transpose: [K][N] f32 -> [N][K] bf16 ---------
__global__ __launch_bounds__(256) void cvt_w(
    const float* __restrict__ src, short* __restrict__ dst, int K, int N) {
  __shared__ float tile[64][68];
  const int n0 = blockIdx.x * 64;
  const int k0 = blockIdx.y * 64;
  const int tid = threadIdx.x;
  #pragma unroll
  for (int i = 0; i < 16; ++i) {
    const int e = i * 256 + tid;
    const int kk = e >> 6, nn = e & 63;
    tile[kk][nn] = src[(size_t)(k0 + kk) * N + n0 + nn];
  }
  __syncthreads();
  #pragma unroll
  for (int i = 0; i < 2; ++i) {
    const int e = i * 256 + tid;
    const int nn = e >> 3, kc = (e & 7) * 8;
    short8 s;
    #pragma unroll
    for (int j = 0; j < 8; ++j) s[j] = (short)f2bf(tile[kc + j][nn]);
    *(short8*)(dst + (size_t)(n0 + nn) * K + k0 + kc) = s;
  }
}

// ---- hh_w [128][512] f32 -> packed f16 pairs hh2[k2][512], k2 = k/2 --------
__global__ __launch_bounds__(256) void cvt_hh(
    const float* __restrict__ hhw, h2f* __restrict__ hh2) {
  const int idx = blockIdx.x * 256 + threadIdx.x;   // 32768 total
  const int k2 = idx >> 9, j = idx & 511;
  h2f v;
  v.x = (_Float16)hhw[(size_t)(2 * k2) * 512 + j];
  v.y = (_Float16)hhw[(size_t)(2 * k2 + 1) * 512 + j];
  hh2[idx] = v;
}

// --------------------------- head projection GEMM --------------------------
__global__ __launch_bounds__(256) void proj_gemm(
    const float* __restrict__ x, const float* __restrict__ mu1,
    const float* __restrict__ rs1, const float* __restrict__ ln1w,
    const float* __restrict__ ln1b, const float* __restrict__ ihw,
    const float* __restrict__ ihb, float* __restrict__ proj, int l0) {
  __shared__ __align__(16) float As[64][68];
  __shared__ __align__(16) float Bs[64][128];
  const int h  = blockIdx.z;
  const int n0 = blockIdx.y * 128;
  const int m0 = blockIdx.x * 64;
  const int tid = threadIdx.x;
  const int tm = (tid >> 5) << 3;
  const int tn = (tid & 31) << 2;
  float acc[8][4] = {};
  const float* Bb = ihw + (size_t)h * DPH * 512;
  for (int k0 = 0; k0 < DPH; k0 += 64) {
    #pragma unroll
    for (int i = 0; i < 4; ++i) {
      int idx = tid + i * 256;
      int r = idx >> 4, kk = (idx & 15) << 2;
      const int rowm = m0 + r;
      const int l = l0 + (rowm >> 3), b = rowm & 7;
      const int grow = b * SEQ + l;
      const float4 v = *(const float4*)(x + (size_t)grow * D_MODEL + h * DPH + k0 + kk);
      const float mu = mu1[grow], rs = rs1[grow];
      const float4 wv = *(const float4*)(ln1w + h * DPH + k0 + kk);
      const float4 bv = *(const float4*)(ln1b + h * DPH + k0 + kk);
      float4 o;
      o.x = (v.x - mu) * rs * wv.x + bv.x;
      o.y = (v.y - mu) * rs * wv.y + bv.y;
      o.z = (v.z - mu) * rs * wv.z + bv.z;
      o.w = (v.w - mu) * rs * wv.w + bv.w;
      *(float4*)&As[r][kk] = o;
    }
    #pragma unroll
    for (int i = 0; i < 8; ++i) {
      int idx = tid + i * 256;
      int kk = idx >> 5, nn = (idx & 31) << 2;
      *(float4*)&Bs[kk][nn] = *(const float4*)(Bb + (size_t)(k0 + kk) * 512 + n0 + nn);
    }
    __syncthreads();
    #pragma unroll 4
    for (int kk = 0; kk < 64; ++kk) {
      float a[8];
      #pragma unroll
      for (int i = 0; i < 8; ++i) a[i] = As[tm + i][kk];
      const float4 bv = *(const float4*)&Bs[kk][tn];
      #pragma unroll
      for (int i = 0; i < 8; ++i) {
        acc[i][0] += a[i] * bv.x; acc[i][1] += a[i] * bv.y;
        acc[i][2] += a[i] * bv.z; acc[i][3] += a[i] * bv.w;
      }
    }
    __syncthreads();
  }
  const float4 bias = *(const float4*)(ihb + h * 512 + n0 + tn);
  #pragma unroll
  for (int i = 0; i < 8; ++i) {
    const int rowm = m0 + tm + i;
    float4 o;
    o.x = acc[i][0] + bias.x; o.y = acc[i][1] + bias.y;
    o.z = acc[i][2] + bias.z; o.w = acc[i][3] + bias.w;
    *(float4*)(proj + ((size_t)rowm * NHEAD + h) * 512 + n0 + tn) = o;
  }
}

// ------------------------------- sLSTM scan --------------------------------
// 64 blocks (1 chain each), 512 threads / 8 waves. Lane l of wave w owns
// matvec column (l&3)*128 + 16w + (l>>2); its quad holds all 4 gates of
// channel 16w + (l>>2). Per step: broadcast-read h (16 x ds_read_b128) ->
// 64 dot2 -> 4 DPP quad broadcasts -> gate_step -> h16 write (g==0 lanes) ->
// one barrier. proj staged per 32-step group (global_load_lds, dbuf); h
// staged in LDS and dumped coalesced once per group.
__global__ __launch_bounds__(512, 1) void scan_chunk(
    const float* __restrict__ proj, const h2f* __restrict__ hh2,
    float* __restrict__ state, float* __restrict__ hout, int l0) {
  const int bh = blockIdx.x, b = bh >> 3, h = bh & 7;
  const int tid = threadIdx.x;
  const int l = tid & 63, w = tid >> 6;
  const int g = l & 3, chl = l >> 2;
  const int ch = 16 * w + chl;              // this quad's channel
  const int col = g * 128 + ch;             // this lane's matvec column
  __shared__ __align__(16) _Float16 h16[2][128];
  __shared__ __align__(16) float pbuf[2][TGRP][512];   // 128 KB staged proj
  __shared__ __align__(16) float hstage[TGRP][128];    // 16 KB staged h

  // matvec weights: column `col` as 64 packed f16 pairs (64 VGPRs)
  h2f w2[64];
  #pragma unroll
  for (int k2 = 0; k2 < 64; ++k2) w2[k2] = hh2[k2 * 512 + col];

  float c, nrm, m;
  if (l0 == 0) {
    c = 0.0f; nrm = 0.0f; m = -1e30f;
    if (g == 0) h16[0][ch] = (_Float16)0.0f;
  } else {
    c   = state[bh * 128 + ch];
    nrm = state[8192  + bh * 128 + ch];
    m   = state[16384 + bh * 128 + ch];
    if (g == 0) h16[0][ch] = (_Float16)state[24576 + bh * 128 + ch];
  }

  const float* pbase = proj + (size_t)bh * 512;   // step stride 32768 floats

  // stage group GR (32 steps x 512 floats = 64 KB) into pbuf[NB]:
  // 8 half-rows (256 floats) per wave; dst wave-uniform, src per-lane.
  #define STAGE(NB, GR)                                                        \
    {                                                                          \
      _Pragma("unroll")                                                        \
      for (int i = 0; i < 8; ++i) {                                            \
        const int hr = i * 8 + w;                                              \
        const float* src = pbase + (size_t)((GR) * TGRP + (hr >> 1)) * 32768   \
                           + (hr & 1) * 256 + l * 4;                           \
        float* dst = &pbuf[NB][0][0] + hr * 256;                               \
        gll16(src, dst, l);                                                    \
      }                                                                        \
    }

  STAGE(0, 0)
  asm volatile("s_waitcnt vmcnt(0)" ::: "memory");
  __syncthreads();                                   // pbuf[0] + h16[0] ready

  float hv = 0.0f;
  for (int t = 0; t < CHUNK_L; ++t) {
    const int tl = t & (TGRP - 1), gb = (t >> 5) & 1, cur = t & 1;
    // issue next group's staging at group start (drains at step barriers)
    if (tl == 0 && t + TGRP < CHUNK_L) STAGE(gb ^ 1, (t >> 5) + 1)
    // proj term (independent of h; issued early, latency hidden)
    const float pv = pbuf[gb][tl][col];
    // matvec: h16[cur] via broadcast ds_read_b128, 4 independent dot2 chains
    float a0 = 0.0f, a1 = 0.0f, a2 = 0.0f, a3 = 0.0f;
    {
      const h8f* hp = (const h8f*)&h16[cur][0];
      #pragma unroll
      for (int i = 0; i < 4; ++i) {
        H8U u0, u1, u2, u3;
        u0.v = hp[i]; u1.v = hp[4 + i]; u2.v = hp[8 + i]; u3.v = hp[12 + i];
        #pragma unroll
        for (int e = 0; e < 4; ++e) {
          a0 = DOT2(u0.p[e], w2[     4 * i + e], a0);
          a1 = DOT2(u1.p[e], w2[16 + 4 * i + e], a1);
          a2 = DOT2(u2.p[e], w2[32 + 4 * i + e], a2);
          a3 = DOT2(u3.p[e], w2[48 + 4 * i + e], a3);
        }
      }
    }
    const float p = pv + ((a0 + a1) + (a2 + a3));
    // quad allgather: every lane gets all 4 gate pre-activations (VALU DPP)
    const float pi = qbcast<0>(p, l);
    const float pf = qbcast<1>(p, l);
    const float pz = qbcast<2>(p, l);
    const float po = qbcast<3>(p, l);
    hv = gate_step(pi, pf, pz, po, c, nrm, m);       // quad-replicated (free)
    if (g == 0) {
      h16[cur ^ 1][ch] = (_Float16)hv;
      hstage[tl][ch] = hv;
    }
    __syncthreads();                                 // the one barrier per step
    if (tl == TGRP - 1) {
      // coalesced h dump for the finished group: 2 float4 per thread
      const int s = tid >> 4, c8 = (tid & 15) << 3;
      const float4 v0 = *(const float4*)&hstage[s][c8];
      const float4 v1 = *(const float4*)&hstage[s][c8 + 4];
      float* dstp = hout + ((size_t)(b * SEQ + l0 + (t & ~(TGRP - 1)) + s)) * D_MODEL
                    + h * DPH + c8;
      *(float4*)dstp = v0;
      *(float4*)(dstp + 4) = v1;
      __syncthreads();            // dump reads done before next group's writes
    }
  }

  if (g == 0) {
    state[bh * 128 + ch]          = c;
    state[8192  + bh * 128 + ch]  = nrm;
    state[16384 + bh * 128 + ch]  = m;
    state[24576 + bh * 128 + ch]  = hv;
  }
  #undef STAGE
}

// ---------- post: y = headLN(h) + x in place on d_out ; LN2 row stats -------
__global__ __launch_bounds__(256) void post_kernel(
    float* __restrict__ yio, const float* __restrict__ x,
    const float* __restrict__ hnw, const float* __restrict__ hnb,
    float* __restrict__ mu2, float* __restrict__ rs2) {
  const int row = blockIdx.x, tid = threadIdx.x;
  const float4 hv = ((const float4*)(yio + (size_t)row * D_MODEL))[tid];
  float s  = hv.x + hv.y + hv.z + hv.w;
  float s2 = hv.x*hv.x + hv.y*hv.y + hv.z*hv.z + hv.w*hv.w;
  #pragma unroll
  for (int mm = 1; mm < 32; mm <<= 1) {
    s  += __shfl_xor(s,  mm, 32);
    s2 += __shfl_xor(s2, mm, 32);
  }
  const float mu = s * (1.0f / DPH);
  const float var = s2 * (1.0f / DPH) - mu * mu;
  const float rstd = rsqrtf(var + LN_EPS);
  const int dq = tid & 31;
  const float4 w4 = ((const float4*)hnw)[dq];
  const float4 b4 = ((const float4*)hnb)[dq];
  const float4 xv = ((const float4*)(x + (size_t)row * D_MODEL))[tid];
  float4 yv;
  yv.x = (hv.x - mu) * rstd * w4.x + b4.x + xv.x;
  yv.y = (hv.y - mu) * rstd * w4.y + b4.y + xv.y;
  yv.z = (hv.z - mu) * rstd * w4.z + b4.z + xv.z;
  yv.w = (hv.w - mu) * rstd * w4.w + b4.w + xv.w;
  ((float4*)(yio + (size_t)row * D_MODEL))[tid] = yv;
  float t1 = yv.x + yv.y + yv.z + yv.w;
  float t2 = yv.x*yv.x + yv.y*yv.y + yv.z*yv.z + yv.w*yv.w;
  #pragma unroll
  for (int mm = 1; mm < 64; mm <<= 1) {
    t1 += __shfl_xor(t1, mm, 64);
    t2 += __shfl_xor(t2, mm, 64);
  }
  __shared__ float sa[4], sb[4];
  if ((tid & 63) == 0) { sa[tid >> 6] = t1; sb[tid >> 6] = t2; }
  __syncthreads();
  if (tid == 0) {
    const float S  = sa[0] + sa[1] + sa[2] + sa[3];
    const float S2 = sb[0] + sb[1] + sb[2] + sb[3];
    const float m2 = S * (1.0f / D_MODEL);
    const float v2 = S2 * (1.0f / D_MODEL) - m2 * m2;
    mu2[row] = m2;
    rs2[row] = rsqrtf(v2 + LN_EPS);
  }
}

// ------------------------------ FF1 (bf16 MFMA) ------------------------------
__global__ __launch_bounds__(256) void ff1_gemm(
    const float* __restrict__ y, const float* __restrict__ mu2,
    const float* __restrict__ rs2, const float* __restrict__ ln2w,
    const float* __restrict__ ln2b, const short* __restrict__ w1b,
    const float* __restrict__ b1, short* __restrict__ g, int row0) {
  __shared__ short As[128 * 64];
  __shared__ short Bs1[128 * 64];
  __shared__ short Bs2[128 * 64];
  const int tid = threadIdx.x;
  const int m0 = blockIdx.x * 128;
  const int n0 = blockIdx.y * 128;
  const int lane = tid & 63;
  const int wid = tid >> 6, wr = wid >> 1, wc = wid & 1;
  f32x4 acc1[4][4], acc2[4][4];
  #pragma unroll
  for (int i = 0; i < 4; ++i)
    #pragma unroll
    for (int j = 0; j < 4; ++j) { acc1[i][j] = (f32x4)0.0f; acc2[i][j] = (f32x4)0.0f; }
  for (int k0 = 0; k0 < D_MODEL; k0 += 64) {
    #pragma unroll
    for (int i = 0; i < 4; ++i) {
      const int cidx = tid + i * 256;
      const int r = cidx >> 3, c8 = cidx & 7;
      const int grow = row0 + m0 + r;
      const float* src = y + (size_t)grow * D_MODEL + k0 + c8 * 8;
      const float4 v0 = *(const float4*)src;
      const float4 v1 = *(const float4*)(src + 4);
      const float mu = mu2[grow], rs = rs2[grow];
      const float4 w0 = *(const float4*)(ln2w + k0 + c8 * 8);
      const float4 w1 = *(const float4*)(ln2w + k0 + c8 * 8 + 4);
      const float4 bb0 = *(const float4*)(ln2b + k0 + c8 * 8);
      const float4 bb1 = *(const float4*)(ln2b + k0 + c8 * 8 + 4);
      short8 s;
      s[0] = (short)f2bf((v0.x - mu) * rs * w0.x + bb0.x);
      s[1] = (short)f2bf((v0.y - mu) * rs * w0.y + bb0.y);
      s[2] = (short)f2bf((v0.z - mu) * rs * w0.z + bb0.z);
      s[3] = (short)f2bf((v0.w - mu) * rs * w0.w + bb0.w);
      s[4] = (short)f2bf((v1.x - mu) * rs * w1.x + bb1.x);
      s[5] = (short)f2bf((v1.y - mu) * rs * w1.y + bb1.y);
      s[6] = (short)f2bf((v1.z - mu) * rs * w1.z + bb1.z);
      s[7] = (short)f2bf((v1.w - mu) * rs * w1.w + bb1.w);
      *(short8*)&As[r * 64 + ((c8 ^ (r & 7)) << 3)] = s;
    }
    #pragma unroll
    for (int i = 0; i < 4; ++i) {
      const int cidx = tid + i * 256;
      const int r = cidx >> 3, c8 = cidx & 7;
      const short8 sv1 = *(const short8*)(w1b + (size_t)(n0 + r) * D_MODEL + k0 + c8 * 8);
      const short8 sv2 = *(const short8*)(w1b + (size_t)(DFF + n0 + r) * D_MODEL + k0 + c8 * 8);
      const int off = r * 64 + ((c8 ^ (r & 7)) << 3);
      *(short8*)&Bs1[off] = sv1;
      *(short8*)&Bs2[off] = sv2;
    }
    __syncthreads();
    #pragma unroll
    for (int ks = 0; ks < 2; ++ks) {
      short8 af[4], b1f[4], b2f[4];
      #pragma unroll
      for (int mf = 0; mf < 4; ++mf) {
        const int row = wr * 64 + mf * 16 + (lane & 15);
        const int c8 = ks * 4 + (lane >> 4);
        af[mf] = *(const short8*)&As[row * 64 + ((c8 ^ (row & 7)) << 3)];
      }
      #pragma unroll
      for (int nf = 0; nf < 4; ++nf) {
        const int row = wc * 64 + nf * 16 + (lane & 15);
        const int c8 = ks * 4 + (lane >> 4);
        const int off = row * 64 + ((c8 ^ (row & 7)) << 3);
        b1f[nf] = *(const short8*)&Bs1[off];
        b2f[nf] = *(const short8*)&Bs2[off];
      }
      #pragma unroll
      for (int mf = 0; mf < 4; ++mf)
        #pragma unroll
        for (int nf = 0; nf < 4; ++nf) {
          acc1[mf][nf] = __builtin_amdgcn_mfma_f32_16x16x32_bf16(af[mf], b1f[nf], acc1[mf][nf], 0, 0, 0);
          acc2[mf][nf] = __builtin_amdgcn_mfma_f32_16x16x32_bf16(af[mf], b2f[nf], acc2[mf][nf], 0, 0, 0);
        }
    }
    __syncthreads();
  }
  #pragma unroll
  for (int nf = 0; nf < 4; ++nf) {
    const int col = n0 + wc * 64 + nf * 16 + (lane & 15);
    const float bx1 = b1[col], bx2 = b1[DFF + col];
    #pragma unroll
    for (int mf = 0; mf < 4; ++mf) {
      const int rbase = m0 + wr * 64 + mf * 16 + ((lane >> 4) << 2);
      #pragma unroll
      for (int rr = 0; rr < 4; ++rr) {
        const float x1 = acc1[mf][nf][rr] + bx1;
        const float x2 = acc2[mf][nf][rr] + bx2;
        g[(size_t)(rbase + rr) * DFF + col] = (short)f2bf(x1 * gelu_exact(x2));
      }
    }
  }
}

// ----------------- FF2 (bf16 MFMA) + bias + residual, in place --------------
__global__ __launch_bounds__(256) void ff2_gemm(
    const short* __restrict__ g, const short* __restrict__ w2b,
    const float* __restrict__ b2, float* __restrict__ out, int row0) {
  __shared__ short As[128 * 64];
  __shared__ short Bs[128 * 64];
  const int tid = threadIdx.x;
  const int m0 = blockIdx.x * 128;
  const int n0 = blockIdx.y * 128;
  const int lane = tid & 63;
  const int wid = tid >> 6, wr = wid >> 1, wc = wid & 1;
  f32x4 acc[4][4];
  #pragma unroll
  for (int i = 0; i < 4; ++i)
    #pragma unroll
    for (int j = 0; j < 4; ++j) acc[i][j] = (f32x4)0.0f;
  for (int k0 = 0; k0 < DFF; k0 += 64) {
    #pragma unroll
    for (int i = 0; i < 4; ++i) {
      const int cidx = tid + i * 256;
      const int r = cidx >> 3, c8 = cidx & 7;
      const int off = r * 64 + ((c8 ^ (r & 7)) << 3);
      *(short8*)&As[off] = *(const short8*)(g + (size_t)(m0 + r) * DFF + k0 + c8 * 8);
      *(short8*)&Bs[off] = *(const short8*)(w2b + (size_t)(n0 + r) * DFF + k0 + c8 * 8);
    }
    __syncthreads();
    #pragma unroll
    for (int ks = 0; ks < 2; ++ks) {
      short8 af[4], bf[4];
      #pragma unroll
      for (int mf = 0; mf < 4; ++mf) {
        const int row = wr * 64 + mf * 16 + (lane & 15);
        const int c8 = ks * 4 + (lane >> 4);
        af[mf] = *(const short8*)&As[row * 64 + ((c8 ^ (row & 7)) << 3)];
      }
      #pragma unroll
      for (int nf = 0; nf < 4; ++nf) {
        const int row = wc * 64 + nf * 16 + (lane & 15);
        const int c8 = ks * 4 + (lane >> 4);
        bf[nf] = *(const short8*)&Bs[row * 64 + ((c8 ^ (row & 7)) << 3)];
      }
      #pragma unroll
      for (int mf = 0; mf < 4; ++mf)
        #pragma unroll
        for (int nf = 0; nf < 4; ++nf)
          acc[mf][nf] = __builtin_amdgcn_mfma_f32_16x16x32_bf16(af[mf], bf[nf], acc[mf][nf], 0, 0, 0);
    }
    __syncthreads();
  }
  #pragma unroll
  for (int nf = 0; nf < 4; ++nf) {
    const int col = n0 + wc * 64 + nf * 16 + (lane & 15);
    const float bias = b2[col];
    #pragma unroll
    for (int mf = 0; mf < 4; ++mf) {
      const int rbase = row0 + m0 + wr * 64 + mf * 16 + ((lane >> 4) << 2);
      #pragma unroll
      for (int rr = 0; rr < 4; ++rr) {
        float* p = out + (size_t)(rbase + rr) * D_MODEL + col;
        *p = acc[mf][nf][rr] + bias + *p;
      }
    }
  }
}

// ------------------------------- launcher -----------------------------------
extern "C" void kernel_launch(void* const* d_in, const int* in_sizes, int n_in,
                              void* d_out, int out_size, void* d_ws, size_t ws_size,
                              hipStream_t stream) {
  const float* x    = (const float*)d_in[0];
  const float* ihw  = (const float*)d_in[1];
  const float* ihb  = (const float*)d_in[2];
  const float* hhw  = (const float*)d_in[3];
  const float* ln1w = (const float*)d_in[4];
  const float* ln1b = (const float*)d_in[5];
  const float* hnw  = (const float*)d_in[6];
  const float* hnb  = (const float*)d_in[7];
  const float* ln2w = (const float*)d_in[8];
  const float* ln2b = (const float*)d_in[9];
  const float* ffw1 = (const float*)d_in[10];
  const float* ffb1 = (const float*)d_in[11];
  const float* ffw2 = (const float*)d_in[12];
  const float* ffb2 = (const float*)d_in[13];

  float* ws    = (float*)d_ws;
  float* r0    = ws;                    // 8388608 floats: proj fp32 / g bf16
  float* state = ws + 8388608;          // 32768
  float* mu1   = ws + 8421376;
  float* rs1   = ws + 8437760;
  float* mu2   = ws + 8454144;
  float* rs2   = ws + 8470528;
  short* w1b   = (short*)(ws + 8486912);   // 4096x1024 bf16 (8 MB)
  short* w2b   = (short*)(ws + 10584064);  // 1024x2048 bf16 (4 MB)
  h2f*   hh2   = (h2f*)(ws + 11632640);    // 64x512 packed f16 pairs (128 KB)
  short* gb    = (short*)r0;               // 8192x2048 bf16 chunk (32 MB)
  float* out   = (float*)d_out;

  cvt_w<<<dim3(4096 / 64, 1024 / 64), 256, 0, stream>>>(ffw1, w1b, 1024, 4096);
  cvt_w<<<dim3(1024 / 64, 2048 / 64), 256, 0, stream>>>(ffw2, w2b, 2048, 1024);
  cvt_hh<<<128, 256, 0, stream>>>(hhw, hh2);
  ln_stats_kernel<<<NROWS, 256, 0, stream>>>(x, mu1, rs1);
  for (int cidx = 0; cidx < SEQ / CHUNK_L; ++cidx) {
    const int l0 = cidx * CHUNK_L;
    proj_gemm<<<dim3(CHUNK_L * BATCH / 64, 512 / 128, NHEAD), 256, 0, stream>>>(
        x, mu1, rs1, ln1w, ln1b, ihw, ihb, r0, l0);
    scan_chunk<<<BATCH * NHEAD, 512, 0, stream>>>(r0, hh2, state, out, l0);
  }
  post_kernel<<<NROWS, 256, 0, stream>>>(out, x, hnw, hnb, mu2, rs2);
  for (int rc = 0; rc < NROWS / ROWCH; ++rc) {
    const int row0 = rc * ROWCH;
    ff1_gemm<<<dim3(ROWCH / 128, DFF / 128), 256, 0, stream>>>(
        out, mu2, rs2, ln2w, ln2b, w1b, ffb1, gb, row0);
    ff2_gemm<<<dim3(ROWCH / 128, D_MODEL / 128), 256, 0, stream>>>(
        gb, w2b, ffb2, out, row0);
  }
}

// Round 13
// 2352.058 us; speedup vs baseline: 1.7993x; 1.0853x over previous
//
#include <hip/hip_runtime.h>
#include <math.h>

// ---------------------------------------------------------------------------
// sLSTM block, round 13: K-split quad scan. Lane (w, p=l>>2, q=l&3) computes
// K-quarter q of all 4 gate columns of channel ch=16w+p (4x16 dot2). A quad
// butterfly (2 DPP-xor stages, elementwise on 4 partials) leaves EVERY lane
// holding all 4 gate totals -> gate_step directly. h-broadcast shrinks from
// 16 to 4 ds_read_b128 instructions per wave per step (the r12-measured LDS
// instruction pipe was the binding constraint). proj staged per 32-step group
// (global_load_lds, dbuf); h dumped coalesced per group; one barrier/step.
// FFN = bf16 MFMA (unchanged).
// Workspace (floats): r0 32MB | state 128KB | mu/rs 256KB | w1b 8MB | w2b 4MB
//                     | hh2 128KB   (~44.6 MB)
// ---------------------------------------------------------------------------

#define D_MODEL 1024
#define NHEAD   8
#define DPH     128
#define DFF     2048
#define BATCH   8
#define SEQ     2048
#define NROWS   (BATCH * SEQ)   // 16384
#define CHUNK_L 256             // scan steps per launch (8 launches)
#define TGRP    32              // steps per staged group
#define ROWCH   8192            // FFN rows per chunk (2 chunks)
#define LN_EPS  1e-5f

typedef __attribute__((ext_vector_type(8))) short short8;
typedef __attribute__((ext_vector_type(4))) float f32x4;
typedef __attribute__((ext_vector_type(2))) _Float16 h2f;
typedef __attribute__((ext_vector_type(8))) _Float16 h8f;
union H8U { h8f v; h2f p[4]; };

#if __has_builtin(__builtin_amdgcn_fdot2)
#define DOT2(a, b, c) __builtin_amdgcn_fdot2((a), (b), (c), false)
#else
__device__ __forceinline__ float DOT2(h2f a, h2f b, float c) {
  return c + (float)a.x * (float)b.x + (float)a.y * (float)b.y;
}
#endif

// quad_perm lane-xor swaps (VALU DPP; no LDS)
__device__ __forceinline__ float qxor1(float v) {
#if __has_builtin(__builtin_amdgcn_update_dpp)
  union { float f; int i; } u; u.f = v;
  u.i = __builtin_amdgcn_update_dpp(u.i, u.i, 0xB1, 0xf, 0xf, true);  // [1,0,3,2]
  return u.f;
#else
  return __shfl_xor(v, 1, 64);
#endif
}
__device__ __forceinline__ float qxor2(float v) {
#if __has_builtin(__builtin_amdgcn_update_dpp)
  union { float f; int i; } u; u.f = v;
  u.i = __builtin_amdgcn_update_dpp(u.i, u.i, 0x4E, 0xf, 0xf, true);  // [2,3,0,1]
  return u.f;
#else
  return __shfl_xor(v, 2, 64);
#endif
}

// async global->LDS, 16B per lane; lds_base must be WAVE-UNIFORM (HW adds lane*16)
__device__ __forceinline__ void gll16(const float* src, float* lds_base, int lane) {
#if __has_builtin(__builtin_amdgcn_global_load_lds)
  __builtin_amdgcn_global_load_lds(
      (const __attribute__((address_space(1))) unsigned int*)src,
      (__attribute__((address_space(3))) unsigned int*)lds_base, 16, 0, 0);
#else
  *(float4*)((char*)lds_base + lane * 16) = *(const float4*)src;
#endif
}

__device__ __forceinline__ float gelu_exact(float x) {
  return 0.5f * x * (1.0f + erff(x * 0.70710678118654752440f));
}

__device__ __forceinline__ unsigned short f2bf(float f) {
  union { float f; unsigned int u; } v; v.f = f;
  unsigned int r = v.u + 0x7fffu + ((v.u >> 16) & 1u);
  return (unsigned short)(r >> 16);
}

// one sLSTM gate update for one channel; returns raw h
__device__ __forceinline__ float gate_step(float iv, float fv, float zraw, float oraw,
                                           float& c, float& nrm, float& m) {
  const float zv = 1.0f - 2.0f / (__expf(2.0f * zraw) + 1.0f);
  const float ov = 1.0f / (1.0f + __expf(-oraw));
  const float lf = fminf(fv, 0.0f) - __logf(1.0f + __expf(-fabsf(fv)));
  const float ft = lf + m;
  const float mn = fmaxf(ft, iv);
  const float is = __expf(iv - mn);
  const float fs = __expf(ft - mn);
  c = fs * c + is * zv;
  nrm = fs * nrm + is;
  m = mn;
  return ov * (c / nrm);
}

// --------------------- per-row LN stats (mu, rstd) --------------------------
__global__ __launch_bounds__(256) void ln_stats_kernel(
    const float* __restrict__ in, float* __restrict__ mu_out,
    float* __restrict__ rs_out) {
  const int row = blockIdx.x, tid = threadIdx.x;
  const float4 v = ((const float4*)(in + (size_t)row * D_MODEL))[tid];
  float s  = v.x + v.y + v.z + v.w;
  float s2 = v.x*v.x + v.y*v.y + v.z*v.z + v.w*v.w;
  #pragma unroll
  for (int m = 1; m < 64; m <<= 1) { s += __shfl_xor(s, m, 64); s2 += __shfl_xor(s2, m, 64); }
  __shared__ float sa[4], sb[4];
  if ((tid & 63) == 0) { sa[tid >> 6] = s; sb[tid >> 6] = s2; }
  __syncthreads();
  if (tid == 0) {
    const float S  = sa[0] + sa[1] + sa[2] + sa[3];
    const float S2 = sb[0] + sb[1] + sb[2] + sb[3];
    const float mu = S * (1.0f / D_MODEL);
    const float var = S2 * (1.0f / D_MODEL) - mu * mu;
    mu_out[row] = mu;
    rs_out[row] = rsqrtf(var + LN_EPS);
  }
}

// -------------- weight convert+transpose: [K][N] f32 -> [N][K] bf16 ---------
__global__ __launch_bounds__(256) void cvt_w(
    const float* __restrict__ src, short* __restrict__ dst, int K, int N) {
  __shared__ float tile[64][68];
  const int n0 = blockIdx.x * 64;
  const int k0 = blockIdx.y * 64;
  const int tid = threadIdx.x;
  #pragma unroll
  for (int i = 0; i < 16; ++i) {
    const int e = i * 256 + tid;
    const int kk = e >> 6, nn = e & 63;
    tile[kk][nn] = src[(size_t)(k0 + kk) * N + n0 + nn];
  }
  __syncthreads();
  #pragma unroll
  for (int i = 0; i < 2; ++i) {
    const int e = i * 256 + tid;
    const int nn = e >> 3, kc = (e & 7) * 8;
    short8 s;
    #pragma unroll
    for (int j = 0; j < 8; ++j) s[j] = (short)f2bf(tile[kc + j][nn]);
    *(short8*)(dst + (size_t)(n0 + nn) * K + k0 + kc) = s;
  }
}

// ---- hh_w [128][512] f32 -> packed f16 pairs hh2[k2][512], k2 = k/2 --------
__global__ __launch_bounds__(256) void cvt_hh(
    const float* __restrict__ hhw, h2f* __restrict__ hh2) {
  const int idx = blockIdx.x * 256 + threadIdx.x;   // 32768 total
  const int k2 = idx >> 9, j = idx & 511;
  h2f v;
  v.x = (_Float16)hhw[(size_t)(2 * k2) * 512 + j];
  v.y = (_Float16)hhw[(size_t)(2 * k2 + 1) * 512 + j];
  hh2[idx] = v;
}

// --------------------------- head projection GEMM --------------------------
__global__ __launch_bounds__(256) void proj_gemm(
    const float* __restrict__ x, const float* __restrict__ mu1,
    const float* __restrict__ rs1, const float* __restrict__ ln1w,
    const float* __restrict__ ln1b, const float* __restrict__ ihw,
    const float* __restrict__ ihb, float* __restrict__ proj, int l0) {
  __shared__ __align__(16) float As[64][68];
  __shared__ __align__(16) float Bs[64][128];
  const int h  = blockIdx.z;
  const int n0 = blockIdx.y * 128;
  const int m0 = blockIdx.x * 64;
  const int tid = threadIdx.x;
  const int tm = (tid >> 5) << 3;
  const int tn = (tid & 31) << 2;
  float acc[8][4] = {};
  const float* Bb = ihw + (size_t)h * DPH * 512;
  for (int k0 = 0; k0 < DPH; k0 += 64) {
    #pragma unroll
    for (int i = 0; i < 4; ++i) {
      int idx = tid + i * 256;
      int r = idx >> 4, kk = (idx & 15) << 2;
      const int rowm = m0 + r;
      const int l = l0 + (rowm >> 3), b = rowm & 7;
      const int grow = b * SEQ + l;
      const float4 v = *(const float4*)(x + (size_t)grow * D_MODEL + h * DPH + k0 + kk);
      const float mu = mu1[grow], rs = rs1[grow];
      const float4 wv = *(const float4*)(ln1w + h * DPH + k0 + kk);
      const float4 bv = *(const float4*)(ln1b + h * DPH + k0 + kk);
      float4 o;
      o.x = (v.x - mu) * rs * wv.x + bv.x;
      o.y = (v.y - mu) * rs * wv.y + bv.y;
      o.z = (v.z - mu) * rs * wv.z + bv.z;
      o.w = (v.w - mu) * rs * wv.w + bv.w;
      *(float4*)&As[r][kk] = o;
    }
    #pragma unroll
    for (int i = 0; i < 8; ++i) {
      int idx = tid + i * 256;
      int kk = idx >> 5, nn = (idx & 31) << 2;
      *(float4*)&Bs[kk][nn] = *(const float4*)(Bb + (size_t)(k0 + kk) * 512 + n0 + nn);
    }
    __syncthreads();
    #pragma unroll 4
    for (int kk = 0; kk < 64; ++kk) {
      float a[8];
      #pragma unroll
      for (int i = 0; i < 8; ++i) a[i] = As[tm + i][kk];
      const float4 bv = *(const float4*)&Bs[kk][tn];
      #pragma unroll
      for (int i = 0; i < 8; ++i) {
        acc[i][0] += a[i] * bv.x; acc[i][1] += a[i] * bv.y;
        acc[i][2] += a[i] * bv.z; acc[i][3] += a[i] * bv.w;
      }
    }
    __syncthreads();
  }
  const float4 bias = *(const float4*)(ihb + h * 512 + n0 + tn);
  #pragma unroll
  for (int i = 0; i < 8; ++i) {
    const int rowm = m0 + tm + i;
    float4 o;
    o.x = acc[i][0] + bias.x; o.y = acc[i][1] + bias.y;
    o.z = acc[i][2] + bias.z; o.w = acc[i][3] + bias.w;
    *(float4*)(proj + ((size_t)rowm * NHEAD + h) * 512 + n0 + tn) = o;
  }
}

// ------------------------------- sLSTM scan --------------------------------
// 64 blocks (1 chain each), 512 threads / 8 waves. Lane (w, p=l>>2, q=l&3)
// computes K-quarter q of the 4 gate columns {j*128 + 16w+p}. Quad butterfly
// (2 DPP stages) -> all lanes hold all 4 gate totals -> gate_step. h16 writes
// by q==0 lanes only (non-redundant). One barrier/step.
__global__ __launch_bounds__(512, 1) void scan_chunk(
    const float* __restrict__ proj, const h2f* __restrict__ hh2,
    float* __restrict__ state, float* __restrict__ hout, int l0) {
  const int bh = blockIdx.x, b = bh >> 3, h = bh & 7;
  const int tid = threadIdx.x;
  const int l = tid & 63, w = tid >> 6;
  const int q = l & 3, p = l >> 2;
  const int ch = 16 * w + p;                // this quad's channel
  __shared__ __align__(16) _Float16 h16[2][128];
  __shared__ __align__(16) float pbuf[2][TGRP][512];   // 128 KB staged proj
  __shared__ __align__(16) float hstage[TGRP][128];    // 16 KB staged h

  // weights: w2[j][kk] = hh_w pair (k = 32q + 2kk .. +1) of column j*128+ch
  h2f w2[4][16];
  #pragma unroll
  for (int j = 0; j < 4; ++j)
    #pragma unroll
    for (int kk = 0; kk < 16; ++kk)
      w2[j][kk] = hh2[(size_t)(16 * q + kk) * 512 + j * 128 + ch];

  float c, nrm, m;
  if (l0 == 0) {
    c = 0.0f; nrm = 0.0f; m = -1e30f;
    if (q == 0 && w == 0) { h16[0][p] = (_Float16)0.0f; }
    if (q == 0) h16[0][ch] = (_Float16)0.0f;
  } else {
    c   = state[bh * 128 + ch];
    nrm = state[8192  + bh * 128 + ch];
    m   = state[16384 + bh * 128 + ch];
    if (q == 0) h16[0][ch] = (_Float16)state[24576 + bh * 128 + ch];
  }

  const float* pbase = proj + (size_t)bh * 512;   // step stride 32768 floats

  // stage group GR (32 steps x 512 floats = 64 KB) into pbuf[NB]:
  // 8 half-rows (256 floats) per wave; dst wave-uniform, src per-lane.
  #define STAGE(NB, GR)                                                        \
    {                                                                          \
      _Pragma("unroll")                                                        \
      for (int i = 0; i < 8; ++i) {                                            \
        const int hr = i * 8 + w;                                              \
        const float* src = pbase + (size_t)((GR) * TGRP + (hr >> 1)) * 32768   \
                           + (hr & 1) * 256 + l * 4;                           \
        float* dst = &pbuf[NB][0][0] + hr * 256;                               \
        gll16(src, dst, l);                                                    \
      }                                                                        \
    }

  STAGE(0, 0)
  asm volatile("s_waitcnt vmcnt(0)" ::: "memory");
  __syncthreads();                                   // pbuf[0] + h16[0] ready

  float hv = 0.0f;
  for (int t = 0; t < CHUNK_L; ++t) {
    const int tl = t & (TGRP - 1), gb = (t >> 5) & 1, cur = t & 1;
    if (tl == 0 && t + TGRP < CHUNK_L) STAGE(gb ^ 1, (t >> 5) + 1)
    // partial dots over this lane's K-quarter for the 4 gate columns
    float pa0 = 0.0f, pa1 = 0.0f, pa2 = 0.0f, pa3 = 0.0f;
    {
      const h8f* hp = (const h8f*)&h16[cur][q * 32];   // 4 x ds_read_b128
      #pragma unroll
      for (int i = 0; i < 4; ++i) {
        H8U u; u.v = hp[i];
        #pragma unroll
        for (int e = 0; e < 4; ++e) {
          const int kk = i * 4 + e;
          pa0 = DOT2(u.p[e], w2[0][kk], pa0);
          pa1 = DOT2(u.p[e], w2[1][kk], pa1);
          pa2 = DOT2(u.p[e], w2[2][kk], pa2);
          pa3 = DOT2(u.p[e], w2[3][kk], pa3);
        }
      }
    }
    // proj term: lane q contributes column q*128+ch into slot q
    const float pv = pbuf[gb][tl][q * 128 + ch];
    pa0 += (q == 0) ? pv : 0.0f;
    pa1 += (q == 1) ? pv : 0.0f;
    pa2 += (q == 2) ? pv : 0.0f;
    pa3 += (q == 3) ? pv : 0.0f;
    // quad butterfly: elementwise sum over the 4 K-quarters (VALU DPP)
    pa0 += qxor1(pa0); pa1 += qxor1(pa1); pa2 += qxor1(pa2); pa3 += qxor1(pa3);
    pa0 += qxor2(pa0); pa1 += qxor2(pa1); pa2 += qxor2(pa2); pa3 += qxor2(pa3);
    // gates (all lanes of the quad compute identically -- free)
    hv = gate_step(pa0, pa1, pa2, pa3, c, nrm, m);
    if (q == 0) {
      h16[cur ^ 1][ch] = (_Float16)hv;
      hstage[tl][ch] = hv;
    }
    __syncthreads();                                 // the one barrier per step
    if (tl == TGRP - 1) {
      // coalesced h dump for the finished group: 2 float4 per thread
      const int s = tid >> 4, c8 = (tid & 15) << 3;
      const float4 v0 = *(const float4*)&hstage[s][c8];
      const float4 v1 = *(const float4*)&hstage[s][c8 + 4];
      float* dstp = hout + ((size_t)(b * SEQ + l0 + (t & ~(TGRP - 1)) + s)) * D_MODEL
                    + h * DPH + c8;
      *(float4*)dstp = v0;
      *(float4*)(dstp + 4) = v1;
      __syncthreads();            // dump reads done before next group's writes
    }
  }

  if (q == 0) {
    state[bh * 128 + ch]          = c;
    state[8192  + bh * 128 + ch]  = nrm;
    state[16384 + bh * 128 + ch]  = m;
    state[24576 + bh * 128 + ch]  = hv;
  }
  #undef STAGE
}

// ---------- post: y = headLN(h) + x in place on d_out ; LN2 row stats -------
__global__ __launch_bounds__(256) void post_kernel(
    float* __restrict__ yio, const float* __restrict__ x,
    const float* __restrict__ hnw, const float* __restrict__ hnb,
    float* __restrict__ mu2, float* __restrict__ rs2) {
  const int row = blockIdx.x, tid = threadIdx.x;
  const float4 hv = ((const float4*)(yio + (size_t)row * D_MODEL))[tid];
  float s  = hv.x + hv.y + hv.z + hv.w;
  float s2 = hv.x*hv.x + hv.y*hv.y + hv.z*hv.z + hv.w*hv.w;
  #pragma unroll
  for (int mm = 1; mm < 32; mm <<= 1) {
    s  += __shfl_xor(s,  mm, 32);
    s2 += __shfl_xor(s2, mm, 32);
  }
  const float mu = s * (1.0f / DPH);
  const float var = s2 * (1.0f / DPH) - mu * mu;
  const float rstd = rsqrtf(var + LN_EPS);
  const int dq = tid & 31;
  const float4 w4 = ((const float4*)hnw)[dq];
  const float4 b4 = ((const float4*)hnb)[dq];
  const float4 xv = ((const float4*)(x + (size_t)row * D_MODEL))[tid];
  float4 yv;
  yv.x = (hv.x - mu) * rstd * w4.x + b4.x + xv.x;
  yv.y = (hv.y - mu) * rstd * w4.y + b4.y + xv.y;
  yv.z = (hv.z - mu) * rstd * w4.z + b4.z + xv.z;
  yv.w = (hv.w - mu) * rstd * w4.w + b4.w + xv.w;
  ((float4*)(yio + (size_t)row * D_MODEL))[tid] = yv;
  float t1 = yv.x + yv.y + yv.z + yv.w;
  float t2 = yv.x*yv.x + yv.y*yv.y + yv.z*yv.z + yv.w*yv.w;
  #pragma unroll
  for (int mm = 1; mm < 64; mm <<= 1) {
    t1 += __shfl_xor(t1, mm, 64);
    t2 += __shfl_xor(t2, mm, 64);
  }
  __shared__ float sa[4], sb[4];
  if ((tid & 63) == 0) { sa[tid >> 6] = t1; sb[tid >> 6] = t2; }
  __syncthreads();
  if (tid == 0) {
    const float S  = sa[0] + sa[1] + sa[2] + sa[3];
    const float S2 = sb[0] + sb[1] + sb[2] + sb[3];
    const float m2 = S * (1.0f / D_MODEL);
    const float v2 = S2 * (1.0f / D_MODEL) - m2 * m2;
    mu2[row] = m2;
    rs2[row] = rsqrtf(v2 + LN_EPS);
  }
}

// ------------------------------ FF1 (bf16 MFMA) ------------------------------
__global__ __launch_bounds__(256) void ff1_gemm(
    const float* __restrict__ y, const float* __restrict__ mu2,
    const float* __restrict__ rs2, const float* __restrict__ ln2w,
    const float* __restrict__ ln2b, const short* __restrict__ w1b,
    const float* __restrict__ b1, short* __restrict__ g, int row0) {
  __shared__ short As[128 * 64];
  __shared__ short Bs1[128 * 64];
  __shared__ short Bs2[128 * 64];
  const int tid = threadIdx.x;
  const int m0 = blockIdx.x * 128;
  const int n0 = blockIdx.y * 128;
  const int lane = tid & 63;
  const int wid = tid >> 6, wr = wid >> 1, wc = wid & 1;
  f32x4 acc1[4][4], acc2[4][4];
  #pragma unroll
  for (int i = 0; i < 4; ++i)
    #pragma unroll
    for (int j = 0; j < 4; ++j) { acc1[i][j] = (f32x4)0.0f; acc2[i][j] = (f32x4)0.0f; }
  for (int k0 = 0; k0 < D_MODEL; k0 += 64) {
    #pragma unroll
    for (int i = 0; i < 4; ++i) {
      const int cidx = tid + i * 256;
      const int r = cidx >> 3, c8 = cidx & 7;
      const int grow = row0 + m0 + r;
      const float* src = y + (size_t)grow * D_MODEL + k0 + c8 * 8;
      const float4 v0 = *(const float4*)src;
      const float4 v1 = *(const float4*)(src + 4);
      const float mu = mu2[grow], rs = rs2[grow];
      const float4 w0 = *(const float4*)(ln2w + k0 + c8 * 8);
      const float4 w1 = *(const float4*)(ln2w + k0 + c8 * 8 + 4);
      const float4 bb0 = *(const float4*)(ln2b + k0 + c8 * 8);
      const float4 bb1 = *(const float4*)(ln2b + k0 + c8 * 8 + 4);
      short8 s;
      s[0] = (short)f2bf((v0.x - mu) * rs * w0.x + bb0.x);
      s[1] = (short)f2bf((v0.y - mu) * rs * w0.y + bb0.y);
      s[2] = (short)f2bf((v0.z - mu) * rs * w0.z + bb0.z);
      s[3] = (short)f2bf((v0.w - mu) * rs * w0.w + bb0.w);
      s[4] = (short)f2bf((v1.x - mu) * rs * w1.x + bb1.x);
      s[5] = (short)f2bf((v1.y - mu) * rs * w1.y + bb1.y);
      s[6] = (short)f2bf((v1.z - mu) * rs * w1.z + bb1.z);
      s[7] = (short)f2bf((v1.w - mu) * rs * w1.w + bb1.w);
      *(short8*)&As[r * 64 + ((c8 ^ (r & 7)) << 3)] = s;
    }
    #pragma unroll
    for (int i = 0; i < 4; ++i) {
      const int cidx = tid + i * 256;
      const int r = cidx >> 3, c8 = cidx & 7;
      const short8 sv1 = *(const short8*)(w1b + (size_t)(n0 + r) * D_MODEL + k0 + c8 * 8);
      const short8 sv2 = *(const short8*)(w1b + (size_t)(DFF + n0 + r) * D_MODEL + k0 + c8 * 8);
      const int off = r * 64 + ((c8 ^ (r & 7)) << 3);
      *(short8*)&Bs1[off] = sv1;
      *(short8*)&Bs2[off] = sv2;
    }
    __syncthreads();
    #pragma unroll
    for (int ks = 0; ks < 2; ++ks) {
      short8 af[4], b1f[4], b2f[4];
      #pragma unroll
      for (int mf = 0; mf < 4; ++mf) {
        const int row = wr * 64 + mf * 16 + (lane & 15);
        const int c8 = ks * 4 + (lane >> 4);
        af[mf] = *(const short8*)&As[row * 64 + ((c8 ^ (row & 7)) << 3)];
      }
      #pragma unroll
      for (int nf = 0; nf < 4; ++nf) {
        const int row = wc * 64 + nf * 16 + (lane & 15);
        const int c8 = ks * 4 + (lane >> 4);
        const int off = row * 64 + ((c8 ^ (row & 7)) << 3);
        b1f[nf] = *(const short8*)&Bs1[off];
        b2f[nf] = *(const short8*)&Bs2[off];
      }
      #pragma unroll
      for (int mf = 0; mf < 4; ++mf)
        #pragma unroll
        for (int nf = 0; nf < 4; ++nf) {
          acc1[mf][nf] = __builtin_amdgcn_mfma_f32_16x16x32_bf16(af[mf], b1f[nf], acc1[mf][nf], 0, 0, 0);
          acc2[mf][nf] = __builtin_amdgcn_mfma_f32_16x16x32_bf16(af[mf], b2f[nf], acc2[mf][nf], 0, 0, 0);
        }
    }
    __syncthreads();
  }
  #pragma unroll
  for (int nf = 0; nf < 4; ++nf) {
    const int col = n0 + wc * 64 + nf * 16 + (lane & 15);
    const float bx1 = b1[col], bx2 = b1[DFF + col];
    #pragma unroll
    for (int mf = 0; mf < 4; ++mf) {
      const int rbase = m0 + wr * 64 + mf * 16 + ((lane >> 4) << 2);
      #pragma unroll
      for (int rr = 0; rr < 4; ++rr) {
        const float x1 = acc1[mf][nf][rr] + bx1;
        const float x2 = acc2[mf][nf][rr] + bx2;
        g[(size_t)(rbase + rr) * DFF + col] = (short)f2bf(x1 * gelu_exact(x2));
      }
    }
  }
}

// ----------------- FF2 (bf16 MFMA) + bias + residual, in place --------------
__global__ __launch_bounds__(256) void ff2_gemm(
    const short* __restrict__ g, const short* __restrict__ w2b,
    const float* __restrict__ b2, float* __restrict__ out, int row0) {
  __shared__ short As[128 * 64];
  __shared__ short Bs[128 * 64];
  const int tid = threadIdx.x;
  const int m0 = blockIdx.x * 128;
  const int n0 = blockIdx.y * 128;
  const int lane = tid & 63;
  const int wid = tid >> 6, wr = wid >> 1, wc = wid & 1;
  f32x4 acc[4][4];
  #pragma unroll
  for (int i = 0; i < 4; ++i)
    #pragma unroll
    for (int j = 0; j < 4; ++j) acc[i][j] = (f32x4)0.0f;
  for (int k0 = 0; k0 < DFF; k0 += 64) {
    #pragma unroll
    for (int i = 0; i < 4; ++i) {
      const int cidx = tid + i * 256;
      const int r = cidx >> 3, c8 = cidx & 7;
      const int off = r * 64 + ((c8 ^ (r & 7)) << 3);
      *(short8*)&As[off] = *(const short8*)(g + (size_t)(m0 + r) * DFF + k0 + c8 * 8);
      *(short8*)&Bs[off] = *(const short8*)(w2b + (size_t)(n0 + r) * DFF + k0 + c8 * 8);
    }
    __syncthreads();
    #pragma unroll
    for (int ks = 0; ks < 2; ++ks) {
      short8 af[4], bf[4];
      #pragma unroll
      for (int mf = 0; mf < 4; ++mf) {
        const int row = wr * 64 + mf * 16 + (lane & 15);
        const int c8 = ks * 4 + (lane >> 4);
        af[mf] = *(const short8*)&As[row * 64 + ((c8 ^ (row & 7)) << 3)];
      }
      #pragma unroll
      for (int nf = 0; nf < 4; ++nf) {
        const int row = wc * 64 + nf * 16 + (lane & 15);
        const int c8 = ks * 4 + (lane >> 4);
        bf[nf] = *(const short8*)&Bs[row * 64 + ((c8 ^ (row & 7)) << 3)];
      }
      #pragma unroll
      for (int mf = 0; mf < 4; ++mf)
        #pragma unroll
        for (int nf = 0; nf < 4; ++nf)
          acc[mf][nf] = __builtin_amdgcn_mfma_f32_16x16x32_bf16(af[mf], bf[nf], acc[mf][nf], 0, 0, 0);
    }
    __syncthreads();
  }
  #pragma unroll
  for (int nf = 0; nf < 4; ++nf) {
    const int col = n0 + wc * 64 + nf * 16 + (lane & 15);
    const float bias = b2[col];
    #pragma unroll
    for (int mf = 0; mf < 4; ++mf) {
      const int rbase = row0 + m0 + wr * 64 + mf * 16 + ((lane >> 4) << 2);
      #pragma unroll
      for (int rr = 0; rr < 4; ++rr) {
        float* p = out + (size_t)(rbase + rr) * D_MODEL + col;
        *p = acc[mf][nf][rr] + bias + *p;
      }
    }
  }
}

// ------------------------------- launcher -----------------------------------
extern "C" void kernel_launch(void* const* d_in, const int* in_sizes, int n_in,
                              void* d_out, int out_size, void* d_ws, size_t ws_size,
                              hipStream_t stream) {
  const float* x    = (const float*)d_in[0];
  const float* ihw  = (const float*)d_in[1];
  const float* ihb  = (const float*)d_in[2];
  const float* hhw  = (const float*)d_in[3];
  const float* ln1w = (const float*)d_in[4];
  const float* ln1b = (const float*)d_in[5];
  const float* hnw  = (const float*)d_in[6];
  const float* hnb  = (const float*)d_in[7];
  const float* ln2w = (const float*)d_in[8];
  const float* ln2b = (const float*)d_in[9];
  const float* ffw1 = (const float*)d_in[10];
  const float* ffb1 = (const float*)d_in[11];
  const float* ffw2 = (const float*)d_in[12];
  const float* ffb2 = (const float*)d_in[13];

  float* ws    = (float*)d_ws;
  float* r0    = ws;                    // 8388608 floats: proj fp32 / g bf16
  float* state = ws + 8388608;          // 32768
  float* mu1   = ws + 8421376;
  float* rs1   = ws + 8437760;
  float* mu2   = ws + 8454144;
  float* rs2   = ws + 8470528;
  short* w1b   = (short*)(ws + 8486912);   // 4096x1024 bf16 (8 MB)
  short* w2b   = (short*)(ws + 10584064);  // 1024x2048 bf16 (4 MB)
  h2f*   hh2   = (h2f*)(ws + 11632640);    // 64x512 packed f16 pairs (128 KB)
  short* gb    = (short*)r0;               // 8192x2048 bf16 chunk (32 MB)
  float* out   = (float*)d_out;

  cvt_w<<<dim3(4096 / 64, 1024 / 64), 256, 0, stream>>>(ffw1, w1b, 1024, 4096);
  cvt_w<<<dim3(1024 / 64, 2048 / 64), 256, 0, stream>>>(ffw2, w2b, 2048, 1024);
  cvt_hh<<<128, 256, 0, stream>>>(hhw, hh2);
  ln_stats_kernel<<<NROWS, 256, 0, stream>>>(x, mu1, rs1);
  for (int cidx = 0; cidx < SEQ / CHUNK_L; ++cidx) {
    const int l0 = cidx * CHUNK_L;
    proj_gemm<<<dim3(CHUNK_L * BATCH / 64, 512 / 128, NHEAD), 256, 0, stream>>>(
        x, mu1, rs1, ln1w, ln1b, ihw, ihb, r0, l0);
    scan_chunk<<<BATCH * NHEAD, 512, 0, stream>>>(r0, hh2, state, out, l0);
  }
  post_kernel<<<NROWS, 256, 0, stream>>>(out, x, hnw, hnb, mu2, rs2);
  for (int rc = 0; rc < NROWS / ROWCH; ++rc) {
    const int row0 = rc * ROWCH;
    ff1_gemm<<<dim3(ROWCH / 128, DFF / 128), 256, 0, stream>>>(
        out, mu2, rs2, ln2w, ln2b, w1b, ffb1, gb, row0);
    ff2_gemm<<<dim3(ROWCH / 128, D_MODEL / 128), 256, 0, stream>>>(
        gb, w2b, ffb2, out, row0);
  }
}

// Round 14
// 2011.808 us; speedup vs baseline: 2.1036x; 1.1691x over previous
//
#include <hip/hip_runtime.h>
#include <math.h>

// ---------------------------------------------------------------------------
// sLSTM block, round 14: r13's K-split quad scan with (1) fully-unrolled step
// groups (compile-time LDS offsets), (2) v_rcp_f32 replacing all 3 divisions
// in the gate math, (3) +8q bank-rotation on the proj gate-read path (applied
// at proj_gemm write time; 4-way conflict -> conflict-free). hstage double-
// buffered (no group-end barrier). FFN = bf16 MFMA (unchanged).
// Workspace (floats): r0 32MB | state 128KB | mu/rs 256KB | w1b 8MB | w2b 4MB
//                     | hh2 128KB   (~44.6 MB)
// ---------------------------------------------------------------------------

#define D_MODEL 1024
#define NHEAD   8
#define DPH     128
#define DFF     2048
#define BATCH   8
#define SEQ     2048
#define NROWS   (BATCH * SEQ)   // 16384
#define CHUNK_L 256             // scan steps per launch (8 launches)
#define TGRP    16              // steps per staged group (unrolled)
#define NGRP    (CHUNK_L / TGRP)
#define ROWCH   8192            // FFN rows per chunk (2 chunks)
#define LN_EPS  1e-5f

typedef __attribute__((ext_vector_type(8))) short short8;
typedef __attribute__((ext_vector_type(4))) float f32x4;
typedef __attribute__((ext_vector_type(2))) _Float16 h2f;
typedef __attribute__((ext_vector_type(8))) _Float16 h8f;
union H8U { h8f v; h2f p[4]; };

#if __has_builtin(__builtin_amdgcn_fdot2)
#define DOT2(a, b, c) __builtin_amdgcn_fdot2((a), (b), (c), false)
#else
__device__ __forceinline__ float DOT2(h2f a, h2f b, float c) {
  return c + (float)a.x * (float)b.x + (float)a.y * (float)b.y;
}
#endif

#if __has_builtin(__builtin_amdgcn_rcpf)
#define FRCP(x) __builtin_amdgcn_rcpf(x)
#else
#define FRCP(x) (1.0f / (x))
#endif

// quad_perm lane-xor swaps (VALU DPP; no LDS)
__device__ __forceinline__ float qxor1(float v) {
#if __has_builtin(__builtin_amdgcn_update_dpp)
  union { float f; int i; } u; u.f = v;
  u.i = __builtin_amdgcn_update_dpp(u.i, u.i, 0xB1, 0xf, 0xf, true);  // [1,0,3,2]
  return u.f;
#else
  return __shfl_xor(v, 1, 64);
#endif
}
__device__ __forceinline__ float qxor2(float v) {
#if __has_builtin(__builtin_amdgcn_update_dpp)
  union { float f; int i; } u; u.f = v;
  u.i = __builtin_amdgcn_update_dpp(u.i, u.i, 0x4E, 0xf, 0xf, true);  // [2,3,0,1]
  return u.f;
#else
  return __shfl_xor(v, 2, 64);
#endif
}

// async global->LDS, 16B per lane; lds_base must be WAVE-UNIFORM (HW adds lane*16)
__device__ __forceinline__ void gll16(const float* src, float* lds_base, int lane) {
#if __has_builtin(__builtin_amdgcn_global_load_lds)
  __builtin_amdgcn_global_load_lds(
      (const __attribute__((address_space(1))) unsigned int*)src,
      (__attribute__((address_space(3))) unsigned int*)lds_base, 16, 0, 0);
#else
  *(float4*)((char*)lds_base + lane * 16) = *(const float4*)src;
#endif
}

__device__ __forceinline__ float gelu_exact(float x) {
  return 0.5f * x * (1.0f + erff(x * 0.70710678118654752440f));
}

__device__ __forceinline__ unsigned short f2bf(float f) {
  union { float f; unsigned int u; } v; v.f = f;
  unsigned int r = v.u + 0x7fffu + ((v.u >> 16) & 1u);
  return (unsigned short)(r >> 16);
}

// one sLSTM gate update (division-free: v_rcp_f32); returns raw h
__device__ __forceinline__ float gate_step(float iv, float fv, float zraw, float oraw,
                                           float& c, float& nrm, float& m) {
  const float zv = 1.0f - 2.0f * FRCP(__expf(2.0f * zraw) + 1.0f);
  const float ov = FRCP(1.0f + __expf(-oraw));
  const float lf = fminf(fv, 0.0f) - __logf(1.0f + __expf(-fabsf(fv)));
  const float ft = lf + m;
  const float mn = fmaxf(ft, iv);
  const float is = __expf(iv - mn);
  const float fs = __expf(ft - mn);
  c = fs * c + is * zv;
  nrm = fs * nrm + is;
  m = mn;
  return ov * c * FRCP(nrm);
}

// --------------------- per-row LN stats (mu, rstd) --------------------------
__global__ __launch_bounds__(256) void ln_stats_kernel(
    const float* __restrict__ in, float* __restrict__ mu_out,
    float* __restrict__ rs_out) {
  const int row = blockIdx.x, tid = threadIdx.x;
  const float4 v = ((const float4*)(in + (size_t)row * D_MODEL))[tid];
  float s  = v.x + v.y + v.z + v.w;
  float s2 = v.x*v.x + v.y*v.y + v.z*v.z + v.w*v.w;
  #pragma unroll
  for (int m = 1; m < 64; m <<= 1) { s += __shfl_xor(s, m, 64); s2 += __shfl_xor(s2, m, 64); }
  __shared__ float sa[4], sb[4];
  if ((tid & 63) == 0) { sa[tid >> 6] = s; sb[tid >> 6] = s2; }
  __syncthreads();
  if (tid == 0) {
    const float S  = sa[0] + sa[1] + sa[2] + sa[3];
    const float S2 = sb[0] + sb[1] + sb[2] + sb[3];
    const float mu = S * (1.0f / D_MODEL);
    const float var = S2 * (1.0f / D_MODEL) - mu * mu;
    mu_out[row] = mu;
    rs_out[row] = rsqrtf(var + LN_EPS);
  }
}

// -------------- weight convert+transpose: [K][N] f32 -> [N][K] bf16 ---------
__global__ __launch_bounds__(256) void cvt_w(
    const float* __restrict__ src, short* __restrict__ dst, int K, int N) {
  __shared__ float tile[64][68];
  const int n0 = blockIdx.x * 64;
  const int k0 = blockIdx.y * 64;
  const int tid = threadIdx.x;
  #pragma unroll
  for (int i = 0; i < 16; ++i) {
    const int e = i * 256 + tid;
    const int kk = e >> 6, nn = e & 63;
    tile[kk][nn] = src[(size_t)(k0 + kk) * N + n0 + nn];
  }
  __syncthreads();
  #pragma unroll
  for (int i = 0; i < 2; ++i) {
    const int e = i * 256 + tid;
    const int nn = e >> 3, kc = (e & 7) * 8;
    short8 s;
    #pragma unroll
    for (int j = 0; j < 8; ++j) s[j] = (short)f2bf(tile[kc + j][nn]);
    *(short8*)(dst + (size_t)(n0 + nn) * K + k0 + kc) = s;
  }
}

// ---- hh_w [128][512] f32 -> packed f16 pairs hh2[k2][512], k2 = k/2 --------
__global__ __launch_bounds__(256) void cvt_hh(
    const float* __restrict__ hhw, h2f* __restrict__ hh2) {
  const int idx = blockIdx.x * 256 + threadIdx.x;   // 32768 total
  const int k2 = idx >> 9, j = idx & 511;
  h2f v;
  v.x = (_Float16)hhw[(size_t)(2 * k2) * 512 + j];
  v.y = (_Float16)hhw[(size_t)(2 * k2 + 1) * 512 + j];
  hh2[idx] = v;
}

// --------------------------- head projection GEMM --------------------------
// Output gate-column n stored at bank-rotated position within its 128-block:
// pos = (n & ~127) + ((n + 8*(n>>7)) & 127)   [q_blk = blockIdx.y = n>>7]
__global__ __launch_bounds__(256) void proj_gemm(
    const float* __restrict__ x, const float* __restrict__ mu1,
    const float* __restrict__ rs1, const float* __restrict__ ln1w,
    const float* __restrict__ ln1b, const float* __restrict__ ihw,
    const float* __restrict__ ihb, float* __restrict__ proj, int l0) {
  __shared__ __align__(16) float As[64][68];
  __shared__ __align__(16) float Bs[64][128];
  const int h  = blockIdx.z;
  const int qb = blockIdx.y;            // 0..3 (gate block)
  const int n0 = qb * 128;
  const int m0 = blockIdx.x * 64;
  const int tid = threadIdx.x;
  const int tm = (tid >> 5) << 3;
  const int tn = (tid & 31) << 2;
  float acc[8][4] = {};
  const float* Bb = ihw + (size_t)h * DPH * 512;
  for (int k0 = 0; k0 < DPH; k0 += 64) {
    #pragma unroll
    for (int i = 0; i < 4; ++i) {
      int idx = tid + i * 256;
      int r = idx >> 4, kk = (idx & 15) << 2;
      const int rowm = m0 + r;
      const int l = l0 + (rowm >> 3), b = rowm & 7;
      const int grow = b * SEQ + l;
      const float4 v = *(const float4*)(x + (size_t)grow * D_MODEL + h * DPH + k0 + kk);
      const float mu = mu1[grow], rs = rs1[grow];
      const float4 wv = *(const float4*)(ln1w + h * DPH + k0 + kk);
      const float4 bv = *(const float4*)(ln1b + h * DPH + k0 + kk);
      float4 o;
      o.x = (v.x - mu) * rs * wv.x + bv.x;
      o.y = (v.y - mu) * rs * wv.y + bv.y;
      o.z = (v.z - mu) * rs * wv.z + bv.z;
      o.w = (v.w - mu) * rs * wv.w + bv.w;
      *(float4*)&As[r][kk] = o;
    }
    #pragma unroll
    for (int i = 0; i < 8; ++i) {
      int idx = tid + i * 256;
      int kk = idx >> 5, nn = (idx & 31) << 2;
      *(float4*)&Bs[kk][nn] = *(const float4*)(Bb + (size_t)(k0 + kk) * 512 + n0 + nn);
    }
    __syncthreads();
    #pragma unroll 4
    for (int kk = 0; kk < 64; ++kk) {
      float a[8];
      #pragma unroll
      for (int i = 0; i < 8; ++i) a[i] = As[tm + i][kk];
      const float4 bv = *(const float4*)&Bs[kk][tn];
      #pragma unroll
      for (int i = 0; i < 8; ++i) {
        acc[i][0] += a[i] * bv.x; acc[i][1] += a[i] * bv.y;
        acc[i][2] += a[i] * bv.z; acc[i][3] += a[i] * bv.w;
      }
    }
    __syncthreads();
  }
  const float4 bias = *(const float4*)(ihb + h * 512 + n0 + tn);
  const int pos = n0 + ((tn + 8 * qb) & 127);     // bank-rotated, float4-safe
  #pragma unroll
  for (int i = 0; i < 8; ++i) {
    const int rowm = m0 + tm + i;
    float4 o;
    o.x = acc[i][0] + bias.x; o.y = acc[i][1] + bias.y;
    o.z = acc[i][2] + bias.z; o.w = acc[i][3] + bias.w;
    *(float4*)(proj + ((size_t)rowm * NHEAD + h) * 512 + pos) = o;
  }
}

// ------------------------------- sLSTM scan --------------------------------
// 64 blocks (1 chain each), 512 threads / 8 waves. Lane (w, p=l>>2, q=l&3)
// computes K-quarter q of the 4 gate columns {j*128 + 16w+p}. Quad butterfly
// (2 DPP stages) -> all lanes hold all 4 gate totals -> gate_step (rcp-based).
// Fully unrolled TGRP=16 step groups (compile-time LDS offsets); pv read at
// bank-rotated offset (conflict-free); hstage double-buffered.
__global__ __launch_bounds__(512, 1) void scan_chunk(
    const float* __restrict__ proj, const h2f* __restrict__ hh2,
    float* __restrict__ state, float* __restrict__ hout, int l0) {
  const int bh = blockIdx.x, b = bh >> 3, h = bh & 7;
  const int tid = threadIdx.x;
  const int l = tid & 63, w = tid >> 6;
  const int q = l & 3, p = l >> 2;
  const int ch = 16 * w + p;                       // this quad's channel
  const int pvoff = q * 128 + ((ch + 8 * q) & 127);  // bank-rotated pv addr
  __shared__ __align__(16) _Float16 h16[2][128];
  __shared__ __align__(16) float pbuf[2][TGRP][512];   // 64 KB staged proj
  __shared__ __align__(16) float hstage[2][TGRP][128]; // 16 KB staged h

  // weights: w2[j][kk] = hh_w pair (k = 32q + 2kk .. +1) of column j*128+ch
  h2f w2[4][16];
  #pragma unroll
  for (int j = 0; j < 4; ++j)
    #pragma unroll
    for (int kk = 0; kk < 16; ++kk)
      w2[j][kk] = hh2[(size_t)(16 * q + kk) * 512 + j * 128 + ch];

  float c, nrm, m;
  if (l0 == 0) {
    c = 0.0f; nrm = 0.0f; m = -1e30f;
    if (q == 0) h16[0][ch] = (_Float16)0.0f;
  } else {
    c   = state[bh * 128 + ch];
    nrm = state[8192  + bh * 128 + ch];
    m   = state[16384 + bh * 128 + ch];
    if (q == 0) h16[0][ch] = (_Float16)state[24576 + bh * 128 + ch];
  }

  const float* pbase = proj + (size_t)bh * 512;   // step stride 32768 floats

  // stage group GR (16 steps x 512 floats = 32 KB) into pbuf[NB]:
  // 4 half-rows (256 floats)... 4 issues x 512 threads x 16B.
  #define STAGE(NB, GR)                                                        \
    {                                                                          \
      _Pragma("unroll")                                                        \
      for (int i = 0; i < 4; ++i) {                                            \
        const int hr = i * 8 + w;                                              \
        const float* src = pbase + (size_t)((GR) * TGRP + (hr >> 1)) * 32768   \
                           + (hr & 1) * 256 + l * 4;                           \
        float* dst = &pbuf[NB][0][0] + hr * 256;                               \
        gll16(src, dst, l);                                                    \
      }                                                                        \
    }

  STAGE(0, 0)
  asm volatile("s_waitcnt vmcnt(0)" ::: "memory");
  __syncthreads();                                   // pbuf[0] + h16[0] ready

  float hv = 0.0f;
  for (int grp = 0; grp < NGRP; ++grp) {
    const int gb = grp & 1;
    if (grp + 1 < NGRP) STAGE(gb ^ 1, grp + 1)       // drains at step barriers
    #pragma unroll
    for (int tl = 0; tl < TGRP; ++tl) {
      const int cur = tl & 1;                        // compile-time
      // partial dots over this lane's K-quarter for the 4 gate columns
      float pa0 = 0.0f, pa1 = 0.0f, pa2 = 0.0f, pa3 = 0.0f;
      {
        const h8f* hp = (const h8f*)&h16[cur][q * 32];   // 4 x ds_read_b128
        #pragma unroll
        for (int i = 0; i < 4; ++i) {
          H8U u; u.v = hp[i];
          #pragma unroll
          for (int e = 0; e < 4; ++e) {
            const int kk = i * 4 + e;
            pa0 = DOT2(u.p[e], w2[0][kk], pa0);
            pa1 = DOT2(u.p[e], w2[1][kk], pa1);
            pa2 = DOT2(u.p[e], w2[2][kk], pa2);
            pa3 = DOT2(u.p[e], w2[3][kk], pa3);
          }
        }
      }
      // proj term (conflict-free rotated read); lane q owns column q*128+ch
      const float pv = pbuf[gb][tl][pvoff];
      pa0 += (q == 0) ? pv : 0.0f;
      pa1 += (q == 1) ? pv : 0.0f;
      pa2 += (q == 2) ? pv : 0.0f;
      pa3 += (q == 3) ? pv : 0.0f;
      // quad butterfly: elementwise sum over the 4 K-quarters (VALU DPP)
      pa0 += qxor1(pa0); pa1 += qxor1(pa1); pa2 += qxor1(pa2); pa3 += qxor1(pa3);
      pa0 += qxor2(pa0); pa1 += qxor2(pa1); pa2 += qxor2(pa2); pa3 += qxor2(pa3);
      hv = gate_step(pa0, pa1, pa2, pa3, c, nrm, m);
      if (q == 0) {
        h16[cur ^ 1][ch] = (_Float16)hv;
        hstage[gb][tl][ch] = hv;
      }
      __syncthreads();                               // the one barrier per step
    }
    // coalesced h dump for the finished group (hstage dbuf -> no extra barrier)
    {
      const int s = tid >> 5, c8 = (tid & 31) << 2;  // 16 steps x 128 ch / 512 thr
      const float4 v0 = *(const float4*)&hstage[gb][s][c8];
      *(float4*)(hout + ((size_t)(b * SEQ + l0 + grp * TGRP + s)) * D_MODEL
                 + h * DPH + c8) = v0;
    }
  }

  if (q == 0) {
    state[bh * 128 + ch]          = c;
    state[8192  + bh * 128 + ch]  = nrm;
    state[16384 + bh * 128 + ch]  = m;
    state[24576 + bh * 128 + ch]  = hv;
  }
  #undef STAGE
}

// ---------- post: y = headLN(h) + x in place on d_out ; LN2 row stats -------
__global__ __launch_bounds__(256) void post_kernel(
    float* __restrict__ yio, const float* __restrict__ x,
    const float* __restrict__ hnw, const float* __restrict__ hnb,
    float* __restrict__ mu2, float* __restrict__ rs2) {
  const int row = blockIdx.x, tid = threadIdx.x;
  const float4 hv = ((const float4*)(yio + (size_t)row * D_MODEL))[tid];
  float s  = hv.x + hv.y + hv.z + hv.w;
  float s2 = hv.x*hv.x + hv.y*hv.y + hv.z*hv.z + hv.w*hv.w;
  #pragma unroll
  for (int mm = 1; mm < 32; mm <<= 1) {
    s  += __shfl_xor(s,  mm, 32);
    s2 += __shfl_xor(s2, mm, 32);
  }
  const float mu = s * (1.0f / DPH);
  const float var = s2 * (1.0f / DPH) - mu * mu;
  const float rstd = rsqrtf(var + LN_EPS);
  const int dq = tid & 31;
  const float4 w4 = ((const float4*)hnw)[dq];
  const float4 b4 = ((const float4*)hnb)[dq];
  const float4 xv = ((const float4*)(x + (size_t)row * D_MODEL))[tid];
  float4 yv;
  yv.x = (hv.x - mu) * rstd * w4.x + b4.x + xv.x;
  yv.y = (hv.y - mu) * rstd * w4.y + b4.y + xv.y;
  yv.z = (hv.z - mu) * rstd * w4.z + b4.z + xv.z;
  yv.w = (hv.w - mu) * rstd * w4.w + b4.w + xv.w;
  ((float4*)(yio + (size_t)row * D_MODEL))[tid] = yv;
  float t1 = yv.x + yv.y + yv.z + yv.w;
  float t2 = yv.x*yv.x + yv.y*yv.y + yv.z*yv.z + yv.w*yv.w;
  #pragma unroll
  for (int mm = 1; mm < 64; mm <<= 1) {
    t1 += __shfl_xor(t1, mm, 64);
    t2 += __shfl_xor(t2, mm, 64);
  }
  __shared__ float sa[4], sb[4];
  if ((tid & 63) == 0) { sa[tid >> 6] = t1; sb[tid >> 6] = t2; }
  __syncthreads();
  if (tid == 0) {
    const float S  = sa[0] + sa[1] + sa[2] + sa[3];
    const float S2 = sb[0] + sb[1] + sb[2] + sb[3];
    const float m2 = S * (1.0f / D_MODEL);
    const float v2 = S2 * (1.0f / D_MODEL) - m2 * m2;
    mu2[row] = m2;
    rs2[row] = rsqrtf(v2 + LN_EPS);
  }
}

// ------------------------------ FF1 (bf16 MFMA) ------------------------------
__global__ __launch_bounds__(256) void ff1_gemm(
    const float* __restrict__ y, const float* __restrict__ mu2,
    const float* __restrict__ rs2, const float* __restrict__ ln2w,
    const float* __restrict__ ln2b, const short* __restrict__ w1b,
    const float* __restrict__ b1, short* __restrict__ g, int row0) {
  __shared__ short As[128 * 64];
  __shared__ short Bs1[128 * 64];
  __shared__ short Bs2[128 * 64];
  const int tid = threadIdx.x;
  const int m0 = blockIdx.x * 128;
  const int n0 = blockIdx.y * 128;
  const int lane = tid & 63;
  const int wid = tid >> 6, wr = wid >> 1, wc = wid & 1;
  f32x4 acc1[4][4], acc2[4][4];
  #pragma unroll
  for (int i = 0; i < 4; ++i)
    #pragma unroll
    for (int j = 0; j < 4; ++j) { acc1[i][j] = (f32x4)0.0f; acc2[i][j] = (f32x4)0.0f; }
  for (int k0 = 0; k0 < D_MODEL; k0 += 64) {
    #pragma unroll
    for (int i = 0; i < 4; ++i) {
      const int cidx = tid + i * 256;
      const int r = cidx >> 3, c8 = cidx & 7;
      const int grow = row0 + m0 + r;
      const float* src = y + (size_t)grow * D_MODEL + k0 + c8 * 8;
      const float4 v0 = *(const float4*)src;
      const float4 v1 = *(const float4*)(src + 4);
      const float mu = mu2[grow], rs = rs2[grow];
      const float4 w0 = *(const float4*)(ln2w + k0 + c8 * 8);
      const float4 w1 = *(const float4*)(ln2w + k0 + c8 * 8 + 4);
      const float4 bb0 = *(const float4*)(ln2b + k0 + c8 * 8);
      const float4 bb1 = *(const float4*)(ln2b + k0 + c8 * 8 + 4);
      short8 s;
      s[0] = (short)f2bf((v0.x - mu) * rs * w0.x + bb0.x);
      s[1] = (short)f2bf((v0.y - mu) * rs * w0.y + bb0.y);
      s[2] = (short)f2bf((v0.z - mu) * rs * w0.z + bb0.z);
      s[3] = (short)f2bf((v0.w - mu) * rs * w0.w + bb0.w);
      s[4] = (short)f2bf((v1.x - mu) * rs * w1.x + bb1.x);
      s[5] = (short)f2bf((v1.y - mu) * rs * w1.y + bb1.y);
      s[6] = (short)f2bf((v1.z - mu) * rs * w1.z + bb1.z);
      s[7] = (short)f2bf((v1.w - mu) * rs * w1.w + bb1.w);
      *(short8*)&As[r * 64 + ((c8 ^ (r & 7)) << 3)] = s;
    }
    #pragma unroll
    for (int i = 0; i < 4; ++i) {
      const int cidx = tid + i * 256;
      const int r = cidx >> 3, c8 = cidx & 7;
      const short8 sv1 = *(const short8*)(w1b + (size_t)(n0 + r) * D_MODEL + k0 + c8 * 8);
      const short8 sv2 = *(const short8*)(w1b + (size_t)(DFF + n0 + r) * D_MODEL + k0 + c8 * 8);
      const int off = r * 64 + ((c8 ^ (r & 7)) << 3);
      *(short8*)&Bs1[off] = sv1;
      *(short8*)&Bs2[off] = sv2;
    }
    __syncthreads();
    #pragma unroll
    for (int ks = 0; ks < 2; ++ks) {
      short8 af[4], b1f[4], b2f[4];
      #pragma unroll
      for (int mf = 0; mf < 4; ++mf) {
        const int row = wr * 64 + mf * 16 + (lane & 15);
        const int c8 = ks * 4 + (lane >> 4);
        af[mf] = *(const short8*)&As[row * 64 + ((c8 ^ (row & 7)) << 3)];
      }
      #pragma unroll
      for (int nf = 0; nf < 4; ++nf) {
        const int row = wc * 64 + nf * 16 + (lane & 15);
        const int c8 = ks * 4 + (lane >> 4);
        const int off = row * 64 + ((c8 ^ (row & 7)) << 3);
        b1f[nf] = *(const short8*)&Bs1[off];
        b2f[nf] = *(const short8*)&Bs2[off];
      }
      #pragma unroll
      for (int mf = 0; mf < 4; ++mf)
        #pragma unroll
        for (int nf = 0; nf < 4; ++nf) {
          acc1[mf][nf] = __builtin_amdgcn_mfma_f32_16x16x32_bf16(af[mf], b1f[nf], acc1[mf][nf], 0, 0, 0);
          acc2[mf][nf] = __builtin_amdgcn_mfma_f32_16x16x32_bf16(af[mf], b2f[nf], acc2[mf][nf], 0, 0, 0);
        }
    }
    __syncthreads();
  }
  #pragma unroll
  for (int nf = 0; nf < 4; ++nf) {
    const int col = n0 + wc * 64 + nf * 16 + (lane & 15);
    const float bx1 = b1[col], bx2 = b1[DFF + col];
    #pragma unroll
    for (int mf = 0; mf < 4; ++mf) {
      const int rbase = m0 + wr * 64 + mf * 16 + ((lane >> 4) << 2);
      #pragma unroll
      for (int rr = 0; rr < 4; ++rr) {
        const float x1 = acc1[mf][nf][rr] + bx1;
        const float x2 = acc2[mf][nf][rr] + bx2;
        g[(size_t)(rbase + rr) * DFF + col] = (short)f2bf(x1 * gelu_exact(x2));
      }
    }
  }
}

// ----------------- FF2 (bf16 MFMA) + bias + residual, in place --------------
__global__ __launch_bounds__(256) void ff2_gemm(
    const short* __restrict__ g, const short* __restrict__ w2b,
    const float* __restrict__ b2, float* __restrict__ out, int row0) {
  __shared__ short As[128 * 64];
  __shared__ short Bs[128 * 64];
  const int tid = threadIdx.x;
  const int m0 = blockIdx.x * 128;
  const int n0 = blockIdx.y * 128;
  const int lane = tid & 63;
  const int wid = tid >> 6, wr = wid >> 1, wc = wid & 1;
  f32x4 acc[4][4];
  #pragma unroll
  for (int i = 0; i < 4; ++i)
    #pragma unroll
    for (int j = 0; j < 4; ++j) acc[i][j] = (f32x4)0.0f;
  for (int k0 = 0; k0 < DFF; k0 += 64) {
    #pragma unroll
    for (int i = 0; i < 4; ++i) {
      const int cidx = tid + i * 256;
      const int r = cidx >> 3, c8 = cidx & 7;
      const int off = r * 64 + ((c8 ^ (r & 7)) << 3);
      *(short8*)&As[off] = *(const short8*)(g + (size_t)(m0 + r) * DFF + k0 + c8 * 8);
      *(short8*)&Bs[off] = *(const short8*)(w2b + (size_t)(n0 + r) * DFF + k0 + c8 * 8);
    }
    __syncthreads();
    #pragma unroll
    for (int ks = 0; ks < 2; ++ks) {
      short8 af[4], bf[4];
      #pragma unroll
      for (int mf = 0; mf < 4; ++mf) {
        const int row = wr * 64 + mf * 16 + (lane & 15);
        const int c8 = ks * 4 + (lane >> 4);
        af[mf] = *(const short8*)&As[row * 64 + ((c8 ^ (row & 7)) << 3)];
      }
      #pragma unroll
      for (int nf = 0; nf < 4; ++nf) {
        const int row = wc * 64 + nf * 16 + (lane & 15);
        const int c8 = ks * 4 + (lane >> 4);
        bf[nf] = *(const short8*)&Bs[row * 64 + ((c8 ^ (row & 7)) << 3)];
      }
      #pragma unroll
      for (int mf = 0; mf < 4; ++mf)
        #pragma unroll
        for (int nf = 0; nf < 4; ++nf)
          acc[mf][nf] = __builtin_amdgcn_mfma_f32_16x16x32_bf16(af[mf], bf[nf], acc[mf][nf], 0, 0, 0);
    }
    __syncthreads();
  }
  #pragma unroll
  for (int nf = 0; nf < 4; ++nf) {
    const int col = n0 + wc * 64 + nf * 16 + (lane & 15);
    const float bias = b2[col];
    #pragma unroll
    for (int mf = 0; mf < 4; ++mf) {
      const int rbase = row0 + m0 + wr * 64 + mf * 16 + ((lane >> 4) << 2);
      #pragma unroll
      for (int rr = 0; rr < 4; ++rr) {
        float* p = out + (size_t)(rbase + rr) * D_MODEL + col;
        *p = acc[mf][nf][rr] + bias + *p;
      }
    }
  }
}

// ------------------------------- launcher -----------------------------------
extern "C" void kernel_launch(void* const* d_in, const int* in_sizes, int n_in,
                              void* d_out, int out_size, void* d_ws, size_t ws_size,
                              hipStream_t stream) {
  const float* x    = (const float*)d_in[0];
  const float* ihw  = (const float*)d_in[1];
  const float* ihb  = (const float*)d_in[2];
  const float* hhw  = (const float*)d_in[3];
  const float* ln1w = (const float*)d_in[4];
  const float* ln1b = (const float*)d_in[5];
  const float* hnw  = (const float*)d_in[6];
  const float* hnb  = (const float*)d_in[7];
  const float* ln2w = (const float*)d_in[8];
  const float* ln2b = (const float*)d_in[9];
  const float* ffw1 = (const float*)d_in[10];
  const float* ffb1 = (const float*)d_in[11];
  const float* ffw2 = (const float*)d_in[12];
  const float* ffb2 = (const float*)d_in[13];

  float* ws    = (float*)d_ws;
  float* r0    = ws;                    // 8388608 floats: proj fp32 / g bf16
  float* state = ws + 8388608;          // 32768
  float* mu1   = ws + 8421376;
  float* rs1   = ws + 8437760;
  float* mu2   = ws + 8454144;
  float* rs2   = ws + 8470528;
  short* w1b   = (short*)(ws + 8486912);   // 4096x1024 bf16 (8 MB)
  short* w2b   = (short*)(ws + 10584064);  // 1024x2048 bf16 (4 MB)
  h2f*   hh2   = (h2f*)(ws + 11632640);    // 64x512 packed f16 pairs (128 KB)
  short* gb    = (short*)r0;               // 8192x2048 bf16 chunk (32 MB)
  float* out   = (float*)d_out;

  cvt_w<<<dim3(4096 / 64, 1024 / 64), 256, 0, stream>>>(ffw1, w1b, 1024, 4096);
  cvt_w<<<dim3(1024 / 64, 2048 / 64), 256, 0, stream>>>(ffw2, w2b, 2048, 1024);
  cvt_hh<<<128, 256, 0, stream>>>(hhw, hh2);
  ln_stats_kernel<<<NROWS, 256, 0, stream>>>(x, mu1, rs1);
  for (int cidx = 0; cidx < SEQ / CHUNK_L; ++cidx) {
    const int l0 = cidx * CHUNK_L;
    proj_gemm<<<dim3(CHUNK_L * BATCH / 64, 512 / 128, NHEAD), 256, 0, stream>>>(
        x, mu1, rs1, ln1w, ln1b, ihw, ihb, r0, l0);
    scan_chunk<<<BATCH * NHEAD, 512, 0, stream>>>(r0, hh2, state, out, l0);
  }
  post_kernel<<<NROWS, 256, 0, stream>>>(out, x, hnw, hnb, mu2, rs2);
  for (int rc = 0; rc < NROWS / ROWCH; ++rc) {
    const int row0 = rc * ROWCH;
    ff1_gemm<<<dim3(ROWCH / 128, DFF / 128), 256, 0, stream>>>(
        out, mu2, rs2, ln2w, ln2b, w1b, ffb1, gb, row0);
    ff2_gemm<<<dim3(ROWCH / 128, D_MODEL / 128), 256, 0, stream>>>(
        gb, w2b, ffb2, out, row0);
  }
}